// Round 1
// baseline (1438.318 us; speedup 1.0000x reference)
//
#include <hip/hip_runtime.h>
#include <hip/hip_bf16.h>
#include <math.h>

#define NN   50000
#define NE   800000
#define NHEAD 4
#define IND  256
#define HIDD 64
#define DD   256   // NHEAD*HIDD
#define NCLS 40

static __device__ __forceinline__ float elu_f(float x) {
  return x > 0.f ? x : expm1f(x);
}
static __device__ __forceinline__ float lrelu_exp(float x) {
  float v = x > 0.f ? x : 0.01f * x;
  return expf(v);
}

// ---- pack W [H][K][HIDD] -> Wp [K][H*HIDD] (row-major K x 256)
__global__ void pack_w(const float* __restrict__ W, float* __restrict__ Wp) {
  int i = blockIdx.x * blockDim.x + threadIdx.x;   // i = k*256 + c
  if (i >= 256 * DD) return;
  int k = i >> 8, c = i & 255;
  Wp[i] = W[(c >> 6) * (256 * HIDD) + k * HIDD + (c & 63)];
}

// ---- classic tiled SGEMM: C[M x Nc] = A[M x K] @ B[K x Nc] + bias[Nc]
__global__ __launch_bounds__(256) void sgemm_bias(
    const float* __restrict__ A, const float* __restrict__ B,
    const float* __restrict__ bias, float* __restrict__ C,
    int M, int Nc, int K) {
  __shared__ float As[16][68];   // [k][m], padded
  __shared__ float Bs[16][64];   // [k][n]
  const int tid = threadIdx.x;
  const int row0 = blockIdx.x * 64;
  const int col0 = blockIdx.y * 64;
  const int tx = tid & 15, ty = tid >> 4;
  const int ar = tid >> 2, akv = (tid & 3) << 2;
  const int bk = tid >> 4, bcv = (tid & 15) << 2;
  const bool fullN = (col0 + 64 <= Nc);
  float acc[4][4] = {};
  for (int k0 = 0; k0 < K; k0 += 16) {
    float4 av = make_float4(0.f, 0.f, 0.f, 0.f);
    if (row0 + ar < M)
      av = *(const float4*)(A + (size_t)(row0 + ar) * K + k0 + akv);
    As[akv + 0][ar] = av.x;
    As[akv + 1][ar] = av.y;
    As[akv + 2][ar] = av.z;
    As[akv + 3][ar] = av.w;
    if (fullN) {
      *(float4*)&Bs[bk][bcv] =
          *(const float4*)(B + (size_t)(k0 + bk) * Nc + col0 + bcv);
    } else {
      float4 bv;
      bv.x = (col0 + bcv + 0 < Nc) ? B[(size_t)(k0 + bk) * Nc + col0 + bcv + 0] : 0.f;
      bv.y = (col0 + bcv + 1 < Nc) ? B[(size_t)(k0 + bk) * Nc + col0 + bcv + 1] : 0.f;
      bv.z = (col0 + bcv + 2 < Nc) ? B[(size_t)(k0 + bk) * Nc + col0 + bcv + 2] : 0.f;
      bv.w = (col0 + bcv + 3 < Nc) ? B[(size_t)(k0 + bk) * Nc + col0 + bcv + 3] : 0.f;
      *(float4*)&Bs[bk][bcv] = bv;
    }
    __syncthreads();
#pragma unroll
    for (int k = 0; k < 16; ++k) {
      float a[4], bb[4];
#pragma unroll
      for (int i = 0; i < 4; i++) a[i] = As[k][ty * 4 + i];
#pragma unroll
      for (int j = 0; j < 4; j++) bb[j] = Bs[k][tx * 4 + j];
#pragma unroll
      for (int i = 0; i < 4; i++)
#pragma unroll
        for (int j = 0; j < 4; j++) acc[i][j] = fmaf(a[i], bb[j], acc[i][j]);
    }
    __syncthreads();
  }
#pragma unroll
  for (int i = 0; i < 4; i++) {
    int r = row0 + ty * 4 + i;
    if (r >= M) continue;
#pragma unroll
    for (int j = 0; j < 4; j++) {
      int c = col0 + tx * 4 + j;
      if (c < Nc) C[(size_t)r * Nc + c] = acc[i][j] + bias[c];
    }
  }
}

// ---- per-node attention scores, 4 heads over 256 dims (one wave per node)
__global__ void attn_scores4(const float* __restrict__ ft,
                             const float* __restrict__ al, const float* __restrict__ alb,
                             const float* __restrict__ ar, const float* __restrict__ arb,
                             float* __restrict__ a1, float* __restrict__ a2, int n_nodes) {
  int n = blockIdx.x * 4 + (threadIdx.x >> 6);
  if (n >= n_nodes) return;
  int lane = threadIdx.x & 63;
  float4 f = *(const float4*)(ft + (size_t)n * 256 + lane * 4);
  float4 l4 = *(const float4*)(al + lane * 4);
  float4 r4 = *(const float4*)(ar + lane * 4);
  float p1 = f.x * l4.x + f.y * l4.y + f.z * l4.z + f.w * l4.w;
  float p2 = f.x * r4.x + f.y * r4.y + f.z * r4.z + f.w * r4.w;
#pragma unroll
  for (int m = 1; m < 16; m <<= 1) {
    p1 += __shfl_xor(p1, m);
    p2 += __shfl_xor(p2, m);
  }
  if ((lane & 15) == 0) {
    int h = lane >> 4;
    a1[n * 4 + h] = p1 + alb[h];
    a2[n * 4 + h] = p2 + arb[h];
  }
}

// ---- final-layer attention scores (1 head over 40 dims)
__global__ void attn_scores1(const float* __restrict__ ftf,
                             const float* __restrict__ alf, const float* __restrict__ alfb,
                             const float* __restrict__ arf, const float* __restrict__ arfb,
                             float* __restrict__ a1, float* __restrict__ a2, int n_nodes) {
  int n = blockIdx.x * 4 + (threadIdx.x >> 6);
  if (n >= n_nodes) return;
  int lane = threadIdx.x & 63;
  float v = (lane < NCLS) ? ftf[(size_t)n * NCLS + lane] : 0.f;
  float p1 = (lane < NCLS) ? v * alf[lane] : 0.f;
  float p2 = (lane < NCLS) ? v * arf[lane] : 0.f;
#pragma unroll
  for (int m = 1; m < 64; m <<= 1) {
    p1 += __shfl_xor(p1, m);
    p2 += __shfl_xor(p2, m);
  }
  if (lane == 0) {
    a1[n] = p1 + alfb[0];
    a2[n] = p2 + arfb[0];
  }
}

// ---- edge weights + denom (4 heads)
__global__ void edge_w4(const int* __restrict__ src, const int* __restrict__ dst,
                        const float* __restrict__ a1, const float* __restrict__ a2,
                        float* __restrict__ w, float* __restrict__ denom) {
  int e = blockIdx.x * blockDim.x + threadIdx.x;
  if (e >= NE) return;
  int s = src[e], d = dst[e];
  float4 as_ = *(const float4*)(a2 + (size_t)s * 4);
  float4 ad = *(const float4*)(a1 + (size_t)d * 4);
  float4 wv;
  wv.x = lrelu_exp(as_.x + ad.x);
  wv.y = lrelu_exp(as_.y + ad.y);
  wv.z = lrelu_exp(as_.z + ad.z);
  wv.w = lrelu_exp(as_.w + ad.w);
  *(float4*)(w + (size_t)e * 4) = wv;
  atomicAdd(&denom[d * 4 + 0], wv.x);
  atomicAdd(&denom[d * 4 + 1], wv.y);
  atomicAdd(&denom[d * 4 + 2], wv.z);
  atomicAdd(&denom[d * 4 + 3], wv.w);
}

// ---- edge weights + denom (1 head)
__global__ void edge_w1(const int* __restrict__ src, const int* __restrict__ dst,
                        const float* __restrict__ a1, const float* __restrict__ a2,
                        float* __restrict__ w, float* __restrict__ denom) {
  int e = blockIdx.x * blockDim.x + threadIdx.x;
  if (e >= NE) return;
  int s = src[e], d = dst[e];
  float wv = lrelu_exp(a2[s] + a1[d]);
  w[e] = wv;
  atomicAdd(&denom[d], wv);
}

// ---- CSR build
__global__ void count_deg(const int* __restrict__ dst, int* __restrict__ deg) {
  int e = blockIdx.x * blockDim.x + threadIdx.x;
  if (e < NE) atomicAdd(&deg[dst[e]], 1);
}

__global__ void scan_deg(const int* __restrict__ deg, int* __restrict__ row_ptr, int n) {
  __shared__ int partials[1024];
  int t = threadIdx.x;
  int chunk = (n + 1023) >> 10;
  int base = t * chunk;
  int lim = min(base + chunk, n);
  int sum = 0;
  for (int i = base; i < lim; ++i) sum += deg[i];
  partials[t] = sum;
  __syncthreads();
  for (int off = 1; off < 1024; off <<= 1) {
    int v = (t >= off) ? partials[t - off] : 0;
    __syncthreads();
    partials[t] += v;
    __syncthreads();
  }
  int run = (t == 0) ? 0 : partials[t - 1];
  if (t == 0) row_ptr[0] = 0;
  for (int i = base; i < lim; ++i) {
    run += deg[i];
    row_ptr[i + 1] = run;
  }
}

__global__ void copy_int(const int* __restrict__ a, int* __restrict__ b, int n) {
  int i = blockIdx.x * blockDim.x + threadIdx.x;
  if (i < n) b[i] = a[i];
}

__global__ void scatter_e(const int* __restrict__ dst, int* __restrict__ cursor,
                          int* __restrict__ eidx) {
  int e = blockIdx.x * blockDim.x + threadIdx.x;
  if (e >= NE) return;
  int d = dst[e];
  int pos = atomicAdd(&cursor[d], 1);
  eidx[pos] = e;
}

// ---- per-dst gather: out[n] = elu(res[n] + sum_e ft[src[e]] * w[e]/denom[n])
template <int D, int NH>
__global__ void gather_k(const float* __restrict__ ft, const float* __restrict__ w,
                         const float* __restrict__ denom, const float* __restrict__ res,
                         const int* __restrict__ row_ptr, const int* __restrict__ eidx,
                         const int* __restrict__ src, float* __restrict__ out) {
  constexpr int CH = 256;
  __shared__ int s_e[CH];
  __shared__ int s_s[CH];
  int n = blockIdx.x;
  int d = threadIdx.x;
  int h = (D == NH * HIDD) ? (d >> 6) : 0;
  int b = row_ptr[n], en = row_ptr[n + 1];
  float acc = 0.f;
  if (res != nullptr && d < D) acc = res[(size_t)n * D + d];
  float invden = 0.f;
  if (en > b && d < D) invden = 1.f / denom[n * NH + h];
  for (int cb = b; cb < en; cb += CH) {
    int cnt = min(CH, en - cb);
    for (int i = threadIdx.x; i < cnt; i += blockDim.x) {
      int e = eidx[cb + i];
      s_e[i] = e;
      s_s[i] = src[e];
    }
    __syncthreads();
    if (d < D) {
      for (int i = 0; i < cnt; ++i) {
        float att = w[(size_t)s_e[i] * NH + h] * invden;
        acc = fmaf(ft[(size_t)s_s[i] * D + d], att, acc);
      }
    }
    __syncthreads();
  }
  if (d < D) out[(size_t)n * D + d] = elu_f(acc);
}

extern "C" void kernel_launch(void* const* d_in, const int* in_sizes, int n_in,
                              void* d_out, int out_size, void* d_ws, size_t ws_size,
                              hipStream_t stream) {
  const float* features = (const float*)d_in[0];
  const int* src = (const int*)d_in[1];
  const int* dst = (const int*)d_in[2];
  const float* W0 = (const float*)d_in[3];
  const float* b0 = (const float*)d_in[4];
  const float* al0 = (const float*)d_in[5];
  const float* alb0 = (const float*)d_in[6];
  const float* ar0 = (const float*)d_in[7];
  const float* arb0 = (const float*)d_in[8];
  const float* W1 = (const float*)d_in[9];
  const float* b1 = (const float*)d_in[10];
  const float* al1 = (const float*)d_in[11];
  const float* alb1 = (const float*)d_in[12];
  const float* ar1 = (const float*)d_in[13];
  const float* arb1 = (const float*)d_in[14];
  const float* R1 = (const float*)d_in[15];
  const float* Rb1 = (const float*)d_in[16];
  const float* Wf = (const float*)d_in[17];
  const float* bfc = (const float*)d_in[18];
  const float* alf = (const float*)d_in[19];
  const float* alfb = (const float*)d_in[20];
  const float* arf = (const float*)d_in[21];
  const float* arfb = (const float*)d_in[22];
  const float* Rf = (const float*)d_in[23];
  const float* Rbf = (const float*)d_in[24];
  float* out = (float*)d_out;

  float* p = (float*)d_ws;
  float* B1 = p;  p += (size_t)NN * 256;
  float* B2 = p;  p += (size_t)NN * 256;
  float* B3 = p;  p += (size_t)NN * 256;
  float* Wp0 = p; p += 65536;
  float* Wp1 = p; p += 65536;
  float* Rp1 = p; p += 65536;
  float* a1 = p;  p += (size_t)NN * 4;
  float* a2 = p;  p += (size_t)NN * 4;
  float* denom = p; p += (size_t)NN * 4;
  float* wbuf = p;  p += (size_t)NE * 4;
  int* ip = (int*)p;
  int* row_ptr = ip; ip += NN + 1;
  int* cursor = ip;  ip += NN;
  int* deg = ip;     ip += NN;
  int* eidx = ip;    ip += NE;

  const int EB = (NE + 255) / 256;

  // weight packing ([H][K][HID] -> [K][H*HID])
  pack_w<<<256, 256, 0, stream>>>(W0, Wp0);
  pack_w<<<256, 256, 0, stream>>>(W1, Wp1);
  pack_w<<<256, 256, 0, stream>>>(R1, Rp1);

  // CSR by dst (built once, reused by all 3 layers)
  hipMemsetAsync(deg, 0, NN * sizeof(int), stream);
  count_deg<<<EB, 256, 0, stream>>>(dst, deg);
  scan_deg<<<1, 1024, 0, stream>>>(deg, row_ptr, NN);
  copy_int<<<(NN + 255) / 256, 256, 0, stream>>>(row_ptr, cursor, NN);
  scatter_e<<<EB, 256, 0, stream>>>(dst, cursor, eidx);

  dim3 g256((NN + 63) / 64, 4);
  dim3 gf((NN + 63) / 64, 1);

  // ---- layer 0
  sgemm_bias<<<g256, 256, 0, stream>>>(features, Wp0, b0, B1, NN, 256, 256);
  attn_scores4<<<(NN + 3) / 4, 256, 0, stream>>>(B1, al0, alb0, ar0, arb0, a1, a2, NN);
  hipMemsetAsync(denom, 0, (size_t)NN * 4 * sizeof(float), stream);
  edge_w4<<<EB, 256, 0, stream>>>(src, dst, a1, a2, wbuf, denom);
  gather_k<256, 4><<<NN, 256, 0, stream>>>(B1, wbuf, denom, nullptr, row_ptr, eidx, src, B2);

  // ---- layer 1 (residual)
  sgemm_bias<<<g256, 256, 0, stream>>>(B2, Wp1, b1, B1, NN, 256, 256);
  sgemm_bias<<<g256, 256, 0, stream>>>(B2, Rp1, Rb1, B3, NN, 256, 256);
  attn_scores4<<<(NN + 3) / 4, 256, 0, stream>>>(B1, al1, alb1, ar1, arb1, a1, a2, NN);
  hipMemsetAsync(denom, 0, (size_t)NN * 4 * sizeof(float), stream);
  edge_w4<<<EB, 256, 0, stream>>>(src, dst, a1, a2, wbuf, denom);
  gather_k<256, 4><<<NN, 256, 0, stream>>>(B1, wbuf, denom, B3, row_ptr, eidx, src, B3);

  // ---- final layer (residual, 1 head, 40 classes)
  sgemm_bias<<<gf, 256, 0, stream>>>(B3, Wf, bfc, B1, NN, NCLS, 256);
  sgemm_bias<<<gf, 256, 0, stream>>>(B3, Rf, Rbf, B2, NN, NCLS, 256);
  attn_scores1<<<(NN + 3) / 4, 256, 0, stream>>>(B1, alf, alfb, arf, arfb, a1, a2, NN);
  hipMemsetAsync(denom, 0, (size_t)NN * sizeof(float), stream);
  edge_w1<<<EB, 256, 0, stream>>>(src, dst, a1, a2, wbuf, denom);
  gather_k<NCLS, 1><<<NN, 64, 0, stream>>>(B1, wbuf, denom, B2, row_ptr, eidx, src, out);
}

// Round 2
// 1011.343 us; speedup vs baseline: 1.4222x; 1.4222x over previous
//
#include <hip/hip_runtime.h>
#include <hip/hip_bf16.h>
#include <math.h>

#define NN   50000
#define NE   800000
#define NHEAD 4
#define IND  256
#define HIDD 64
#define DD   256   // NHEAD*HIDD
#define NCLS 40

static __device__ __forceinline__ float elu_f(float x) {
  return x > 0.f ? x : expm1f(x);
}
static __device__ __forceinline__ float lrelu_exp(float x) {
  float v = x > 0.f ? x : 0.01f * x;
  return expf(v);
}

// ---- pack W [H][K][HIDD] -> Wp [K][H*HIDD] (row-major K x 256)
__global__ void pack_w(const float* __restrict__ W, float* __restrict__ Wp) {
  int i = blockIdx.x * blockDim.x + threadIdx.x;   // i = k*256 + c
  if (i >= 256 * DD) return;
  int k = i >> 8, c = i & 255;
  Wp[i] = W[(c >> 6) * (256 * HIDD) + k * HIDD + (c & 63)];
}

// ---- classic tiled SGEMM: C[M x Nc] = A[M x K] @ B[K x Nc] + bias[Nc]
__global__ __launch_bounds__(256) void sgemm_bias(
    const float* __restrict__ A, const float* __restrict__ B,
    const float* __restrict__ bias, float* __restrict__ C,
    int M, int Nc, int K) {
  __shared__ float As[16][68];   // [k][m], padded
  __shared__ float Bs[16][64];   // [k][n]
  const int tid = threadIdx.x;
  const int row0 = blockIdx.x * 64;
  const int col0 = blockIdx.y * 64;
  const int tx = tid & 15, ty = tid >> 4;
  const int ar = tid >> 2, akv = (tid & 3) << 2;
  const int bk = tid >> 4, bcv = (tid & 15) << 2;
  const bool fullN = (col0 + 64 <= Nc);
  float acc[4][4] = {};
  for (int k0 = 0; k0 < K; k0 += 16) {
    float4 av = make_float4(0.f, 0.f, 0.f, 0.f);
    if (row0 + ar < M)
      av = *(const float4*)(A + (size_t)(row0 + ar) * K + k0 + akv);
    As[akv + 0][ar] = av.x;
    As[akv + 1][ar] = av.y;
    As[akv + 2][ar] = av.z;
    As[akv + 3][ar] = av.w;
    if (fullN) {
      *(float4*)&Bs[bk][bcv] =
          *(const float4*)(B + (size_t)(k0 + bk) * Nc + col0 + bcv);
    } else {
      float4 bv;
      bv.x = (col0 + bcv + 0 < Nc) ? B[(size_t)(k0 + bk) * Nc + col0 + bcv + 0] : 0.f;
      bv.y = (col0 + bcv + 1 < Nc) ? B[(size_t)(k0 + bk) * Nc + col0 + bcv + 1] : 0.f;
      bv.z = (col0 + bcv + 2 < Nc) ? B[(size_t)(k0 + bk) * Nc + col0 + bcv + 2] : 0.f;
      bv.w = (col0 + bcv + 3 < Nc) ? B[(size_t)(k0 + bk) * Nc + col0 + bcv + 3] : 0.f;
      *(float4*)&Bs[bk][bcv] = bv;
    }
    __syncthreads();
#pragma unroll
    for (int k = 0; k < 16; ++k) {
      float a[4], bb[4];
#pragma unroll
      for (int i = 0; i < 4; i++) a[i] = As[k][ty * 4 + i];
#pragma unroll
      for (int j = 0; j < 4; j++) bb[j] = Bs[k][tx * 4 + j];
#pragma unroll
      for (int i = 0; i < 4; i++)
#pragma unroll
        for (int j = 0; j < 4; j++) acc[i][j] = fmaf(a[i], bb[j], acc[i][j]);
    }
    __syncthreads();
  }
#pragma unroll
  for (int i = 0; i < 4; i++) {
    int r = row0 + ty * 4 + i;
    if (r >= M) continue;
#pragma unroll
    for (int j = 0; j < 4; j++) {
      int c = col0 + tx * 4 + j;
      if (c < Nc) C[(size_t)r * Nc + c] = acc[i][j] + bias[c];
    }
  }
}

// ---- per-node attention scores, 4 heads over 256 dims (one wave per node)
__global__ void attn_scores4(const float* __restrict__ ft,
                             const float* __restrict__ al, const float* __restrict__ alb,
                             const float* __restrict__ ar, const float* __restrict__ arb,
                             float* __restrict__ a1, float* __restrict__ a2, int n_nodes) {
  int n = blockIdx.x * 4 + (threadIdx.x >> 6);
  if (n >= n_nodes) return;
  int lane = threadIdx.x & 63;
  float4 f = *(const float4*)(ft + (size_t)n * 256 + lane * 4);
  float4 l4 = *(const float4*)(al + lane * 4);
  float4 r4 = *(const float4*)(ar + lane * 4);
  float p1 = f.x * l4.x + f.y * l4.y + f.z * l4.z + f.w * l4.w;
  float p2 = f.x * r4.x + f.y * r4.y + f.z * r4.z + f.w * r4.w;
#pragma unroll
  for (int m = 1; m < 16; m <<= 1) {
    p1 += __shfl_xor(p1, m);
    p2 += __shfl_xor(p2, m);
  }
  if ((lane & 15) == 0) {
    int h = lane >> 4;
    a1[n * 4 + h] = p1 + alb[h];
    a2[n * 4 + h] = p2 + arb[h];
  }
}

// ---- final-layer attention scores (1 head over 40 dims)
__global__ void attn_scores1(const float* __restrict__ ftf,
                             const float* __restrict__ alf, const float* __restrict__ alfb,
                             const float* __restrict__ arf, const float* __restrict__ arfb,
                             float* __restrict__ a1, float* __restrict__ a2, int n_nodes) {
  int n = blockIdx.x * 4 + (threadIdx.x >> 6);
  if (n >= n_nodes) return;
  int lane = threadIdx.x & 63;
  float v = (lane < NCLS) ? ftf[(size_t)n * NCLS + lane] : 0.f;
  float p1 = (lane < NCLS) ? v * alf[lane] : 0.f;
  float p2 = (lane < NCLS) ? v * arf[lane] : 0.f;
#pragma unroll
  for (int m = 1; m < 64; m <<= 1) {
    p1 += __shfl_xor(p1, m);
    p2 += __shfl_xor(p2, m);
  }
  if (lane == 0) {
    a1[n] = p1 + alfb[0];
    a2[n] = p2 + arfb[0];
  }
}

// ---- CSR build
__global__ void count_deg(const int* __restrict__ dst, int* __restrict__ deg) {
  int e = blockIdx.x * blockDim.x + threadIdx.x;
  if (e < NE) atomicAdd(&deg[dst[e]], 1);
}

__global__ void scan_deg(const int* __restrict__ deg, int* __restrict__ row_ptr, int n) {
  __shared__ int partials[1024];
  int t = threadIdx.x;
  int chunk = (n + 1023) >> 10;
  int base = t * chunk;
  int lim = min(base + chunk, n);
  int sum = 0;
  for (int i = base; i < lim; ++i) sum += deg[i];
  partials[t] = sum;
  __syncthreads();
  for (int off = 1; off < 1024; off <<= 1) {
    int v = (t >= off) ? partials[t - off] : 0;
    __syncthreads();
    partials[t] += v;
    __syncthreads();
  }
  int run = (t == 0) ? 0 : partials[t - 1];
  if (t == 0) row_ptr[0] = 0;
  for (int i = base; i < lim; ++i) {
    run += deg[i];
    row_ptr[i + 1] = run;
  }
}

__global__ void copy_int(const int* __restrict__ a, int* __restrict__ b, int n) {
  int i = blockIdx.x * blockDim.x + threadIdx.x;
  if (i < n) b[i] = a[i];
}

__global__ void scatter_e(const int* __restrict__ dst, int* __restrict__ cursor,
                          int* __restrict__ eidx) {
  int e = blockIdx.x * blockDim.x + threadIdx.x;
  if (e >= NE) return;
  int d = dst[e];
  int pos = atomicAdd(&cursor[d], 1);
  eidx[pos] = e;
}

// ---- fused gather (4 heads, D=256): per dst node, compute edge weights
// from a1/a2, edge-softmax denom via broadcast LDS reads (one head per
// wave -> same-address reads, conflict-free), then weighted ft[src] sum.
// out[n] = elu(res[n] + sum_e ft[src[e]] * w[e]/denom)
__global__ __launch_bounds__(256) void gather_fused4(
    const float* __restrict__ ft, const float* __restrict__ a1,
    const float* __restrict__ a2, const float* __restrict__ res,
    const int* __restrict__ row_ptr, const int* __restrict__ eidx,
    const int* __restrict__ src, float* __restrict__ out) {
  constexpr int CH = 256;
  __shared__ int s_s[CH];
  __shared__ float s_w[CH][4];
  const int n = blockIdx.x;
  const int d = threadIdx.x;
  const int h = d >> 6;          // one head per wave
  const int b = row_ptr[n], en = row_ptr[n + 1];
  const int deg = en - b;
  const float4 a1v = *(const float4*)(a1 + (size_t)n * 4);  // broadcast
  float acc = (res != nullptr) ? res[(size_t)n * DD + d] : 0.f;

  if (deg <= CH) {
    // stage src + per-edge 4-head weights
    for (int i = d; i < deg; i += 256) {
      int s = src[eidx[b + i]];
      s_s[i] = s;
      float4 as_ = *(const float4*)(a2 + (size_t)s * 4);
      float4 wv;
      wv.x = lrelu_exp(as_.x + a1v.x);
      wv.y = lrelu_exp(as_.y + a1v.y);
      wv.z = lrelu_exp(as_.z + a1v.z);
      wv.w = lrelu_exp(as_.w + a1v.w);
      *(float4*)&s_w[i][0] = wv;
    }
    __syncthreads();
    float den = 0.f;
    for (int i = 0; i < deg; ++i) den += s_w[i][h];   // broadcast read
    float invden = (deg > 0) ? 1.f / den : 0.f;
    for (int i = 0; i < deg; ++i)
      acc = fmaf(ft[(size_t)s_s[i] * DD + d], s_w[i][h] * invden, acc);
  } else {
    // fallback (statistically unreachable at avg degree 16): chunked 2-pass
    float den = 0.f;
    for (int cb = b; cb < en; cb += CH) {
      int cnt = min(CH, en - cb);
      for (int i = d; i < cnt; i += 256) {
        int s = src[eidx[cb + i]];
        s_s[i] = s;
        float4 as_ = *(const float4*)(a2 + (size_t)s * 4);
        float4 wv;
        wv.x = lrelu_exp(as_.x + a1v.x);
        wv.y = lrelu_exp(as_.y + a1v.y);
        wv.z = lrelu_exp(as_.z + a1v.z);
        wv.w = lrelu_exp(as_.w + a1v.w);
        *(float4*)&s_w[i][0] = wv;
      }
      __syncthreads();
      for (int i = 0; i < cnt; ++i) den += s_w[i][h];
      __syncthreads();
    }
    float invden = 1.f / den;
    for (int cb = b; cb < en; cb += CH) {
      int cnt = min(CH, en - cb);
      for (int i = d; i < cnt; i += 256) {
        int s = src[eidx[cb + i]];
        s_s[i] = s;
        float4 as_ = *(const float4*)(a2 + (size_t)s * 4);
        float4 wv;
        wv.x = lrelu_exp(as_.x + a1v.x);
        wv.y = lrelu_exp(as_.y + a1v.y);
        wv.z = lrelu_exp(as_.z + a1v.z);
        wv.w = lrelu_exp(as_.w + a1v.w);
        *(float4*)&s_w[i][0] = wv;
      }
      __syncthreads();
      for (int i = 0; i < cnt; ++i)
        acc = fmaf(ft[(size_t)s_s[i] * DD + d], s_w[i][h] * invden, acc);
      __syncthreads();
    }
  }
  out[(size_t)n * DD + d] = elu_f(acc);
}

// ---- fused gather (1 head, D=NCLS=40): 64 threads/block
__global__ __launch_bounds__(64) void gather_fused1(
    const float* __restrict__ ft, const float* __restrict__ a1,
    const float* __restrict__ a2, const float* __restrict__ res,
    const int* __restrict__ row_ptr, const int* __restrict__ eidx,
    const int* __restrict__ src, float* __restrict__ out) {
  constexpr int CH = 256;
  __shared__ int s_s[CH];
  __shared__ float s_w[CH];
  const int n = blockIdx.x;
  const int d = threadIdx.x;
  const int b = row_ptr[n], en = row_ptr[n + 1];
  const int deg = en - b;
  const float a1n = a1[n];
  float acc = (d < NCLS) ? res[(size_t)n * NCLS + d] : 0.f;

  if (deg <= CH) {
    for (int i = d; i < deg; i += 64) {
      int s = src[eidx[b + i]];
      s_s[i] = s;
      s_w[i] = lrelu_exp(a2[s] + a1n);
    }
    __syncthreads();
    float den = 0.f;
    for (int i = 0; i < deg; ++i) den += s_w[i];
    float invden = (deg > 0) ? 1.f / den : 0.f;
    if (d < NCLS)
      for (int i = 0; i < deg; ++i)
        acc = fmaf(ft[(size_t)s_s[i] * NCLS + d], s_w[i] * invden, acc);
  } else {
    float den = 0.f;
    for (int cb = b; cb < en; cb += CH) {
      int cnt = min(CH, en - cb);
      for (int i = d; i < cnt; i += 64) {
        int s = src[eidx[cb + i]];
        s_w[i] = lrelu_exp(a2[s] + a1n);
      }
      __syncthreads();
      for (int i = 0; i < cnt; ++i) den += s_w[i];
      __syncthreads();
    }
    float invden = 1.f / den;
    for (int cb = b; cb < en; cb += CH) {
      int cnt = min(CH, en - cb);
      for (int i = d; i < cnt; i += 64) {
        int s = src[eidx[cb + i]];
        s_s[i] = s;
        s_w[i] = lrelu_exp(a2[s] + a1n);
      }
      __syncthreads();
      if (d < NCLS)
        for (int i = 0; i < cnt; ++i)
          acc = fmaf(ft[(size_t)s_s[i] * NCLS + d], s_w[i] * invden, acc);
      __syncthreads();
    }
  }
  if (d < NCLS) out[(size_t)n * NCLS + d] = elu_f(acc);
}

extern "C" void kernel_launch(void* const* d_in, const int* in_sizes, int n_in,
                              void* d_out, int out_size, void* d_ws, size_t ws_size,
                              hipStream_t stream) {
  const float* features = (const float*)d_in[0];
  const int* src = (const int*)d_in[1];
  const int* dst = (const int*)d_in[2];
  const float* W0 = (const float*)d_in[3];
  const float* b0 = (const float*)d_in[4];
  const float* al0 = (const float*)d_in[5];
  const float* alb0 = (const float*)d_in[6];
  const float* ar0 = (const float*)d_in[7];
  const float* arb0 = (const float*)d_in[8];
  const float* W1 = (const float*)d_in[9];
  const float* b1 = (const float*)d_in[10];
  const float* al1 = (const float*)d_in[11];
  const float* alb1 = (const float*)d_in[12];
  const float* ar1 = (const float*)d_in[13];
  const float* arb1 = (const float*)d_in[14];
  const float* R1 = (const float*)d_in[15];
  const float* Rb1 = (const float*)d_in[16];
  const float* Wf = (const float*)d_in[17];
  const float* bfc = (const float*)d_in[18];
  const float* alf = (const float*)d_in[19];
  const float* alfb = (const float*)d_in[20];
  const float* arf = (const float*)d_in[21];
  const float* arfb = (const float*)d_in[22];
  const float* Rf = (const float*)d_in[23];
  const float* Rbf = (const float*)d_in[24];
  float* out = (float*)d_out;

  float* p = (float*)d_ws;
  float* B1 = p;  p += (size_t)NN * 256;
  float* B2 = p;  p += (size_t)NN * 256;
  float* B3 = p;  p += (size_t)NN * 256;
  float* Wp0 = p; p += 65536;
  float* Wp1 = p; p += 65536;
  float* Rp1 = p; p += 65536;
  float* a1 = p;  p += (size_t)NN * 4;
  float* a2 = p;  p += (size_t)NN * 4;
  int* ip = (int*)p;
  int* row_ptr = ip; ip += NN + 1;
  int* cursor = ip;  ip += NN;
  int* deg = ip;     ip += NN;
  int* eidx = ip;    ip += NE;

  const int EB = (NE + 255) / 256;

  // weight packing ([H][K][HID] -> [K][H*HID])
  pack_w<<<256, 256, 0, stream>>>(W0, Wp0);
  pack_w<<<256, 256, 0, stream>>>(W1, Wp1);
  pack_w<<<256, 256, 0, stream>>>(R1, Rp1);

  // CSR by dst (built once, reused by all 3 layers)
  hipMemsetAsync(deg, 0, NN * sizeof(int), stream);
  count_deg<<<EB, 256, 0, stream>>>(dst, deg);
  scan_deg<<<1, 1024, 0, stream>>>(deg, row_ptr, NN);
  copy_int<<<(NN + 255) / 256, 256, 0, stream>>>(row_ptr, cursor, NN);
  scatter_e<<<EB, 256, 0, stream>>>(dst, cursor, eidx);

  dim3 g256((NN + 63) / 64, 4);
  dim3 gf((NN + 63) / 64, 1);

  // ---- layer 0
  sgemm_bias<<<g256, 256, 0, stream>>>(features, Wp0, b0, B1, NN, 256, 256);
  attn_scores4<<<(NN + 3) / 4, 256, 0, stream>>>(B1, al0, alb0, ar0, arb0, a1, a2, NN);
  gather_fused4<<<NN, 256, 0, stream>>>(B1, a1, a2, nullptr, row_ptr, eidx, src, B2);

  // ---- layer 1 (residual)
  sgemm_bias<<<g256, 256, 0, stream>>>(B2, Wp1, b1, B1, NN, 256, 256);
  sgemm_bias<<<g256, 256, 0, stream>>>(B2, Rp1, Rb1, B3, NN, 256, 256);
  attn_scores4<<<(NN + 3) / 4, 256, 0, stream>>>(B1, al1, alb1, ar1, arb1, a1, a2, NN);
  gather_fused4<<<NN, 256, 0, stream>>>(B1, a1, a2, B3, row_ptr, eidx, src, B3);

  // ---- final layer (residual, 1 head, 40 classes)
  sgemm_bias<<<gf, 256, 0, stream>>>(B3, Wf, bfc, B1, NN, NCLS, 256);
  sgemm_bias<<<gf, 256, 0, stream>>>(B3, Rf, Rbf, B2, NN, NCLS, 256);
  attn_scores1<<<(NN + 3) / 4, 256, 0, stream>>>(B1, alf, alfb, arf, arfb, a1, a2, NN);
  gather_fused1<<<NN, 64, 0, stream>>>(B1, a1, a2, B2, row_ptr, eidx, src, out);
}

// Round 3
// 895.460 us; speedup vs baseline: 1.6062x; 1.1294x over previous
//
#include <hip/hip_runtime.h>
#include <hip/hip_bf16.h>
#include <math.h>

#define NN   50000
#define NE   800000
#define NHEAD 4
#define HIDD 64
#define DD   256   // NHEAD*HIDD
#define NCLS 40

typedef __attribute__((ext_vector_type(8))) short s8v;    // 8 x bf16 bits
typedef __attribute__((ext_vector_type(4))) float f4v;

static __device__ __forceinline__ float elu_f(float x) {
  return x > 0.f ? x : expm1f(x);
}
static __device__ __forceinline__ float lrelu_exp(float x) {
  float v = x > 0.f ? x : 0.01f * x;
  return expf(v);
}
static __device__ __forceinline__ unsigned short f2bf(float x) {
  union { float f; unsigned u; } v; v.f = x;
  unsigned r = v.u + 0x7fffu + ((v.u >> 16) & 1u);   // RNE
  return (unsigned short)(r >> 16);
}
static __device__ __forceinline__ float bf2f(unsigned short b) {
  union { unsigned u; float f; } v; v.u = ((unsigned)b) << 16;
  return v.f;
}

// ---- pack W [H][256][64] -> Bt_hi/lo [n=h*64+c][k] bf16 (row-major n x 256)
__global__ void pack_w_bf(const float* __restrict__ W,
                          unsigned short* __restrict__ Bh,
                          unsigned short* __restrict__ Bl) {
  int i = blockIdx.x * 256 + threadIdx.x;   // i = n*256 + k
  if (i >= 65536) return;
  int n = i >> 8, k = i & 255;
  float v = W[(n >> 6) * (256 * 64) + k * 64 + (n & 63)];
  unsigned short hi = f2bf(v);
  Bh[i] = hi;
  Bl[i] = f2bf(v - bf2f(hi));
}

// ---- pack Wf [256][40] -> [64][256] bf16 hi/lo, zero rows 40..63
__global__ void pack_wf_bf(const float* __restrict__ Wf,
                           unsigned short* __restrict__ Bh,
                           unsigned short* __restrict__ Bl) {
  int i = blockIdx.x * 256 + threadIdx.x;   // i = n*256 + k, n<64
  if (i >= 64 * 256) return;
  int n = i >> 8, k = i & 255;
  float v = (n < NCLS) ? Wf[k * NCLS + n] : 0.f;
  unsigned short hi = f2bf(v);
  Bh[i] = hi;
  Bl[i] = f2bf(v - bf2f(hi));
}

// ---- bf16x3 MFMA GEMM: C[M x Nc] = A[M x 256] @ Bt^T + bias
// Bt stored [Npad][256] bf16 (hi,lo), K fixed at 256, BM=128, BK=32.
// BN = 128 (Nc=256) or 64 (Nc=40 padded to 64).
template <int BN>
__global__ __launch_bounds__(256) void gemm_bf16x3(
    const float* __restrict__ A,
    const unsigned short* __restrict__ Bth, const unsigned short* __restrict__ Btl,
    const float* __restrict__ bias, float* __restrict__ C,
    int M, int Nc) {
  constexpr int K = 256;
  constexpr int RS = 40;                 // LDS row stride (ushorts): 80B -> 2-way max
  constexpr int WM = (BN == 128) ? 2 : 4;   // waves along M
  constexpr int WN = 4 / WM;                // waves along N
  constexpr int MI = (128 / WM) / 16;       // 4 or 2
  constexpr int NI = (BN / WN) / 16;        // 4

  __shared__ unsigned short sAh[128 * RS];
  __shared__ unsigned short sAl[128 * RS];
  __shared__ unsigned short sBh[BN * RS];
  __shared__ unsigned short sBl[BN * RS];

  const int tid = threadIdx.x;
  const int lane = tid & 63;
  const int w = tid >> 6;
  const int wr = w / WN, wc = w % WN;
  const int rowbase = wr * (128 / WM);
  const int colbase = wc * (BN / WN);
  const int row0 = blockIdx.x * 128;
  const int col0 = blockIdx.y * BN;
  const int lm = lane & 15;
  const int lk8 = (lane >> 4) * 8;

  f4v acc[MI][NI];
#pragma unroll
  for (int i = 0; i < MI; i++)
#pragma unroll
    for (int j = 0; j < NI; j++) acc[i][j] = (f4v)(0.f);

  for (int k0 = 0; k0 < K; k0 += 32) {
    __syncthreads();
    // stage A 128x32 f32 -> hi/lo bf16
#pragma unroll
    for (int i = 0; i < 4; ++i) {
      int idx = tid + i * 256;            // 0..1023
      int r = idx >> 3, seg = idx & 7;
      int grow = row0 + r;
      float4 v = make_float4(0.f, 0.f, 0.f, 0.f);
      if (grow < M) v = *(const float4*)(A + (size_t)grow * K + k0 + seg * 4);
      unsigned short h0 = f2bf(v.x), h1 = f2bf(v.y), h2 = f2bf(v.z), h3 = f2bf(v.w);
      ushort4 hv = make_ushort4(h0, h1, h2, h3);
      ushort4 lv = make_ushort4(f2bf(v.x - bf2f(h0)), f2bf(v.y - bf2f(h1)),
                                f2bf(v.z - bf2f(h2)), f2bf(v.w - bf2f(h3)));
      *(ushort4*)&sAh[r * RS + seg * 4] = hv;
      *(ushort4*)&sAl[r * RS + seg * 4] = lv;
    }
    // stage B BNx32 bf16 hi/lo (pre-transposed [n][k])
#pragma unroll
    for (int i = 0; i < BN / 64; ++i) {
      int idx = tid + i * 256;            // < BN*4
      int n = idx >> 2, seg = idx & 3;
      size_t g = (size_t)(col0 + n) * K + k0 + seg * 8;
      *(s8v*)&sBh[n * RS + seg * 8] = *(const s8v*)(Bth + g);
      *(s8v*)&sBl[n * RS + seg * 8] = *(const s8v*)(Btl + g);
    }
    __syncthreads();

    s8v ah[MI], al_[MI], bh[NI], bl_[NI];
#pragma unroll
    for (int mi = 0; mi < MI; ++mi) {
      int base = (rowbase + mi * 16 + lm) * RS + lk8;
      ah[mi] = *(const s8v*)&sAh[base];
      al_[mi] = *(const s8v*)&sAl[base];
    }
#pragma unroll
    for (int ni = 0; ni < NI; ++ni) {
      int base = (colbase + ni * 16 + lm) * RS + lk8;
      bh[ni] = *(const s8v*)&sBh[base];
      bl_[ni] = *(const s8v*)&sBl[base];
    }
    // pass 1: hi*hi
#pragma unroll
    for (int mi = 0; mi < MI; ++mi)
#pragma unroll
      for (int ni = 0; ni < NI; ++ni)
        acc[mi][ni] = __builtin_amdgcn_mfma_f32_16x16x32_bf16(ah[mi], bh[ni], acc[mi][ni], 0, 0, 0);
    // pass 2: hi*lo
#pragma unroll
    for (int mi = 0; mi < MI; ++mi)
#pragma unroll
      for (int ni = 0; ni < NI; ++ni)
        acc[mi][ni] = __builtin_amdgcn_mfma_f32_16x16x32_bf16(ah[mi], bl_[ni], acc[mi][ni], 0, 0, 0);
    // pass 3: lo*hi
#pragma unroll
    for (int mi = 0; mi < MI; ++mi)
#pragma unroll
      for (int ni = 0; ni < NI; ++ni)
        acc[mi][ni] = __builtin_amdgcn_mfma_f32_16x16x32_bf16(al_[mi], bh[ni], acc[mi][ni], 0, 0, 0);
  }

  // epilogue: C = acc + bias  (D map: col=lane&15, row=(lane>>4)*4+r)
#pragma unroll
  for (int ni = 0; ni < NI; ++ni) {
    int col = col0 + colbase + ni * 16 + lm;
    if (col >= Nc) continue;
    float bv = bias[col];
#pragma unroll
    for (int mi = 0; mi < MI; ++mi) {
      int rbase = row0 + rowbase + mi * 16 + (lane >> 4) * 4;
#pragma unroll
      for (int r = 0; r < 4; ++r) {
        int row = rbase + r;
        if (row < M) C[(size_t)row * Nc + col] = acc[mi][ni][r] + bv;
      }
    }
  }
}

// ---- per-node attention scores, 4 heads over 256 dims (one wave per node)
__global__ void attn_scores4(const float* __restrict__ ft,
                             const float* __restrict__ al, const float* __restrict__ alb,
                             const float* __restrict__ ar, const float* __restrict__ arb,
                             float* __restrict__ a1, float* __restrict__ a2, int n_nodes) {
  int n = blockIdx.x * 4 + (threadIdx.x >> 6);
  if (n >= n_nodes) return;
  int lane = threadIdx.x & 63;
  float4 f = *(const float4*)(ft + (size_t)n * 256 + lane * 4);
  float4 l4 = *(const float4*)(al + lane * 4);
  float4 r4 = *(const float4*)(ar + lane * 4);
  float p1 = f.x * l4.x + f.y * l4.y + f.z * l4.z + f.w * l4.w;
  float p2 = f.x * r4.x + f.y * r4.y + f.z * r4.z + f.w * r4.w;
#pragma unroll
  for (int m = 1; m < 16; m <<= 1) {
    p1 += __shfl_xor(p1, m);
    p2 += __shfl_xor(p2, m);
  }
  if ((lane & 15) == 0) {
    int h = lane >> 4;
    a1[n * 4 + h] = p1 + alb[h];
    a2[n * 4 + h] = p2 + arb[h];
  }
}

// ---- final-layer attention scores (1 head over 40 dims)
__global__ void attn_scores1(const float* __restrict__ ftf,
                             const float* __restrict__ alf, const float* __restrict__ alfb,
                             const float* __restrict__ arf, const float* __restrict__ arfb,
                             float* __restrict__ a1, float* __restrict__ a2, int n_nodes) {
  int n = blockIdx.x * 4 + (threadIdx.x >> 6);
  if (n >= n_nodes) return;
  int lane = threadIdx.x & 63;
  float v = (lane < NCLS) ? ftf[(size_t)n * NCLS + lane] : 0.f;
  float p1 = (lane < NCLS) ? v * alf[lane] : 0.f;
  float p2 = (lane < NCLS) ? v * arf[lane] : 0.f;
#pragma unroll
  for (int m = 1; m < 64; m <<= 1) {
    p1 += __shfl_xor(p1, m);
    p2 += __shfl_xor(p2, m);
  }
  if (lane == 0) {
    a1[n] = p1 + alfb[0];
    a2[n] = p2 + arfb[0];
  }
}

// ---- CSR build
__global__ void count_deg(const int* __restrict__ dst, int* __restrict__ deg) {
  int e = blockIdx.x * blockDim.x + threadIdx.x;
  if (e < NE) atomicAdd(&deg[dst[e]], 1);
}

__global__ void scan_deg(const int* __restrict__ deg, int* __restrict__ row_ptr, int n) {
  __shared__ int partials[1024];
  int t = threadIdx.x;
  int chunk = (n + 1023) >> 10;
  int base = t * chunk;
  int lim = min(base + chunk, n);
  int sum = 0;
  for (int i = base; i < lim; ++i) sum += deg[i];
  partials[t] = sum;
  __syncthreads();
  for (int off = 1; off < 1024; off <<= 1) {
    int v = (t >= off) ? partials[t - off] : 0;
    __syncthreads();
    partials[t] += v;
    __syncthreads();
  }
  int run = (t == 0) ? 0 : partials[t - 1];
  if (t == 0) row_ptr[0] = 0;
  for (int i = base; i < lim; ++i) {
    run += deg[i];
    row_ptr[i + 1] = run;
  }
}

__global__ void copy_int(const int* __restrict__ a, int* __restrict__ b, int n) {
  int i = blockIdx.x * blockDim.x + threadIdx.x;
  if (i < n) b[i] = a[i];
}

__global__ void scatter_e(const int* __restrict__ dst, int* __restrict__ cursor,
                          int* __restrict__ eidx) {
  int e = blockIdx.x * blockDim.x + threadIdx.x;
  if (e >= NE) return;
  int d = dst[e];
  int pos = atomicAdd(&cursor[d], 1);
  eidx[pos] = e;
}

// ---- fused gather (4 heads, D=256)
__global__ __launch_bounds__(256) void gather_fused4(
    const float* __restrict__ ft, const float* __restrict__ a1,
    const float* __restrict__ a2, const float* __restrict__ res,
    const int* __restrict__ row_ptr, const int* __restrict__ eidx,
    const int* __restrict__ src, float* __restrict__ out) {
  constexpr int CH = 256;
  __shared__ int s_s[CH];
  __shared__ float s_w[CH][4];
  const int n = blockIdx.x;
  const int d = threadIdx.x;
  const int h = d >> 6;          // one head per wave
  const int b = row_ptr[n], en = row_ptr[n + 1];
  const int deg = en - b;
  const float4 a1v = *(const float4*)(a1 + (size_t)n * 4);
  float acc = (res != nullptr) ? res[(size_t)n * DD + d] : 0.f;

  if (deg <= CH) {
    for (int i = d; i < deg; i += 256) {
      int s = src[eidx[b + i]];
      s_s[i] = s;
      float4 as_ = *(const float4*)(a2 + (size_t)s * 4);
      float4 wv;
      wv.x = lrelu_exp(as_.x + a1v.x);
      wv.y = lrelu_exp(as_.y + a1v.y);
      wv.z = lrelu_exp(as_.z + a1v.z);
      wv.w = lrelu_exp(as_.w + a1v.w);
      *(float4*)&s_w[i][0] = wv;
    }
    __syncthreads();
    float den = 0.f;
    for (int i = 0; i < deg; ++i) den += s_w[i][h];
    float invden = (deg > 0) ? 1.f / den : 0.f;
    for (int i = 0; i < deg; ++i)
      acc = fmaf(ft[(size_t)s_s[i] * DD + d], s_w[i][h] * invden, acc);
  } else {
    float den = 0.f;
    for (int cb = b; cb < en; cb += CH) {
      int cnt = min(CH, en - cb);
      for (int i = d; i < cnt; i += 256) {
        int s = src[eidx[cb + i]];
        float4 as_ = *(const float4*)(a2 + (size_t)s * 4);
        float4 wv;
        wv.x = lrelu_exp(as_.x + a1v.x);
        wv.y = lrelu_exp(as_.y + a1v.y);
        wv.z = lrelu_exp(as_.z + a1v.z);
        wv.w = lrelu_exp(as_.w + a1v.w);
        *(float4*)&s_w[i][0] = wv;
      }
      __syncthreads();
      for (int i = 0; i < cnt; ++i) den += s_w[i][h];
      __syncthreads();
    }
    float invden = 1.f / den;
    for (int cb = b; cb < en; cb += CH) {
      int cnt = min(CH, en - cb);
      for (int i = d; i < cnt; i += 256) {
        int s = src[eidx[cb + i]];
        s_s[i] = s;
        float4 as_ = *(const float4*)(a2 + (size_t)s * 4);
        float4 wv;
        wv.x = lrelu_exp(as_.x + a1v.x);
        wv.y = lrelu_exp(as_.y + a1v.y);
        wv.z = lrelu_exp(as_.z + a1v.z);
        wv.w = lrelu_exp(as_.w + a1v.w);
        *(float4*)&s_w[i][0] = wv;
      }
      __syncthreads();
      for (int i = 0; i < cnt; ++i)
        acc = fmaf(ft[(size_t)s_s[i] * DD + d], s_w[i][h] * invden, acc);
      __syncthreads();
    }
  }
  out[(size_t)n * DD + d] = elu_f(acc);
}

// ---- fused gather (1 head, D=NCLS=40)
__global__ __launch_bounds__(64) void gather_fused1(
    const float* __restrict__ ft, const float* __restrict__ a1,
    const float* __restrict__ a2, const float* __restrict__ res,
    const int* __restrict__ row_ptr, const int* __restrict__ eidx,
    const int* __restrict__ src, float* __restrict__ out) {
  constexpr int CH = 256;
  __shared__ int s_s[CH];
  __shared__ float s_w[CH];
  const int n = blockIdx.x;
  const int d = threadIdx.x;
  const int b = row_ptr[n], en = row_ptr[n + 1];
  const int deg = en - b;
  const float a1n = a1[n];
  float acc = (d < NCLS) ? res[(size_t)n * NCLS + d] : 0.f;

  if (deg <= CH) {
    for (int i = d; i < deg; i += 64) {
      int s = src[eidx[b + i]];
      s_s[i] = s;
      s_w[i] = lrelu_exp(a2[s] + a1n);
    }
    __syncthreads();
    float den = 0.f;
    for (int i = 0; i < deg; ++i) den += s_w[i];
    float invden = (deg > 0) ? 1.f / den : 0.f;
    if (d < NCLS)
      for (int i = 0; i < deg; ++i)
        acc = fmaf(ft[(size_t)s_s[i] * NCLS + d], s_w[i] * invden, acc);
  } else {
    float den = 0.f;
    for (int cb = b; cb < en; cb += CH) {
      int cnt = min(CH, en - cb);
      for (int i = d; i < cnt; i += 64) {
        s_w[i] = lrelu_exp(a2[src[eidx[cb + i]]] + a1n);
      }
      __syncthreads();
      for (int i = 0; i < cnt; ++i) den += s_w[i];
      __syncthreads();
    }
    float invden = 1.f / den;
    for (int cb = b; cb < en; cb += CH) {
      int cnt = min(CH, en - cb);
      for (int i = d; i < cnt; i += 64) {
        int s = src[eidx[cb + i]];
        s_s[i] = s;
        s_w[i] = lrelu_exp(a2[s] + a1n);
      }
      __syncthreads();
      if (d < NCLS)
        for (int i = 0; i < cnt; ++i)
          acc = fmaf(ft[(size_t)s_s[i] * NCLS + d], s_w[i] * invden, acc);
      __syncthreads();
    }
  }
  if (d < NCLS) out[(size_t)n * NCLS + d] = elu_f(acc);
}

extern "C" void kernel_launch(void* const* d_in, const int* in_sizes, int n_in,
                              void* d_out, int out_size, void* d_ws, size_t ws_size,
                              hipStream_t stream) {
  const float* features = (const float*)d_in[0];
  const int* src = (const int*)d_in[1];
  const int* dst = (const int*)d_in[2];
  const float* W0 = (const float*)d_in[3];
  const float* b0 = (const float*)d_in[4];
  const float* al0 = (const float*)d_in[5];
  const float* alb0 = (const float*)d_in[6];
  const float* ar0 = (const float*)d_in[7];
  const float* arb0 = (const float*)d_in[8];
  const float* W1 = (const float*)d_in[9];
  const float* b1 = (const float*)d_in[10];
  const float* al1 = (const float*)d_in[11];
  const float* alb1 = (const float*)d_in[12];
  const float* ar1 = (const float*)d_in[13];
  const float* arb1 = (const float*)d_in[14];
  const float* R1 = (const float*)d_in[15];
  const float* Rb1 = (const float*)d_in[16];
  const float* Wf = (const float*)d_in[17];
  const float* bfc = (const float*)d_in[18];
  const float* alf = (const float*)d_in[19];
  const float* alfb = (const float*)d_in[20];
  const float* arf = (const float*)d_in[21];
  const float* arfb = (const float*)d_in[22];
  const float* Rf = (const float*)d_in[23];
  const float* Rbf = (const float*)d_in[24];
  float* out = (float*)d_out;

  float* p = (float*)d_ws;
  float* B1 = p;  p += (size_t)NN * 256;
  float* B2 = p;  p += (size_t)NN * 256;
  float* B3 = p;  p += (size_t)NN * 256;
  float* a1 = p;  p += (size_t)NN * 4;
  float* a2 = p;  p += (size_t)NN * 4;
  unsigned short* us = (unsigned short*)p;
  unsigned short* Wp0h = us; us += 65536;
  unsigned short* Wp0l = us; us += 65536;
  unsigned short* Wp1h = us; us += 65536;
  unsigned short* Wp1l = us; us += 65536;
  unsigned short* Rp1h = us; us += 65536;
  unsigned short* Rp1l = us; us += 65536;
  unsigned short* Wfh = us;  us += 64 * 256;
  unsigned short* Wfl = us;  us += 64 * 256;
  unsigned short* Rfh = us;  us += 64 * 256;
  unsigned short* Rfl = us;  us += 64 * 256;
  int* ip = (int*)us;
  int* row_ptr = ip; ip += NN + 1;
  int* cursor = ip;  ip += NN;
  int* deg = ip;     ip += NN;
  int* eidx = ip;    ip += NE;

  const int EB = (NE + 255) / 256;

  // weight packing + bf16 hi/lo split ([H][K][HID] -> [n][k])
  pack_w_bf<<<256, 256, 0, stream>>>(W0, Wp0h, Wp0l);
  pack_w_bf<<<256, 256, 0, stream>>>(W1, Wp1h, Wp1l);
  pack_w_bf<<<256, 256, 0, stream>>>(R1, Rp1h, Rp1l);
  pack_wf_bf<<<64, 256, 0, stream>>>(Wf, Wfh, Wfl);
  pack_wf_bf<<<64, 256, 0, stream>>>(Rf, Rfh, Rfl);

  // CSR by dst (built once, reused by all 3 layers)
  hipMemsetAsync(deg, 0, NN * sizeof(int), stream);
  count_deg<<<EB, 256, 0, stream>>>(dst, deg);
  scan_deg<<<1, 1024, 0, stream>>>(deg, row_ptr, NN);
  copy_int<<<(NN + 255) / 256, 256, 0, stream>>>(row_ptr, cursor, NN);
  scatter_e<<<EB, 256, 0, stream>>>(dst, cursor, eidx);

  const int MB = (NN + 127) / 128;   // 391
  dim3 gbig(MB, 2);
  dim3 gsm(MB, 1);

  // ---- layer 0
  gemm_bf16x3<128><<<gbig, 256, 0, stream>>>(features, Wp0h, Wp0l, b0, B1, NN, 256);
  attn_scores4<<<(NN + 3) / 4, 256, 0, stream>>>(B1, al0, alb0, ar0, arb0, a1, a2, NN);
  gather_fused4<<<NN, 256, 0, stream>>>(B1, a1, a2, nullptr, row_ptr, eidx, src, B2);

  // ---- layer 1 (residual)
  gemm_bf16x3<128><<<gbig, 256, 0, stream>>>(B2, Wp1h, Wp1l, b1, B1, NN, 256);
  gemm_bf16x3<128><<<gbig, 256, 0, stream>>>(B2, Rp1h, Rp1l, Rb1, B3, NN, 256);
  attn_scores4<<<(NN + 3) / 4, 256, 0, stream>>>(B1, al1, alb1, ar1, arb1, a1, a2, NN);
  gather_fused4<<<NN, 256, 0, stream>>>(B1, a1, a2, B3, row_ptr, eidx, src, B3);

  // ---- final layer (residual, 1 head, 40 classes)
  gemm_bf16x3<64><<<gsm, 256, 0, stream>>>(B3, Wfh, Wfl, bfc, B1, NN, NCLS);
  gemm_bf16x3<64><<<gsm, 256, 0, stream>>>(B3, Rfh, Rfl, Rbf, B2, NN, NCLS);
  attn_scores1<<<(NN + 3) / 4, 256, 0, stream>>>(B1, alf, alfb, arf, arfb, a1, a2, NN);
  gather_fused1<<<NN, 64, 0, stream>>>(B1, a1, a2, B2, row_ptr, eidx, src, out);
}

// Round 4
// 807.008 us; speedup vs baseline: 1.7823x; 1.1096x over previous
//
#include <hip/hip_runtime.h>
#include <hip/hip_bf16.h>
#include <math.h>

#define NN   50000
#define NE   800000
#define NHEAD 4
#define HIDD 64
#define DD   256   // NHEAD*HIDD
#define NCLS 40

typedef __attribute__((ext_vector_type(8))) short s8v;    // 8 x bf16 bits
typedef __attribute__((ext_vector_type(4))) float f4v;

static __device__ __forceinline__ float elu_f(float x) {
  return x > 0.f ? x : expm1f(x);
}
static __device__ __forceinline__ float lrelu_exp(float x) {
  float v = x > 0.f ? x : 0.01f * x;
  return expf(v);
}
static __device__ __forceinline__ unsigned short f2bf(float x) {
  union { float f; unsigned u; } v; v.f = x;
  unsigned r = v.u + 0x7fffu + ((v.u >> 16) & 1u);   // RNE
  return (unsigned short)(r >> 16);
}
static __device__ __forceinline__ float bf2f(unsigned short b) {
  union { unsigned u; float f; } v; v.u = ((unsigned)b) << 16;
  return v.f;
}
static __device__ __forceinline__ float rdlanef(float v, int l) {
  return __uint_as_float(__builtin_amdgcn_readlane(__float_as_uint(v), l));
}

// ---- pack W [H][256][64] -> Bt_hi/lo [n=h*64+c][k] bf16 (row-major n x 256)
__global__ void pack_w_bf(const float* __restrict__ W,
                          unsigned short* __restrict__ Bh,
                          unsigned short* __restrict__ Bl) {
  int i = blockIdx.x * 256 + threadIdx.x;   // i = n*256 + k
  if (i >= 65536) return;
  int n = i >> 8, k = i & 255;
  float v = W[(n >> 6) * (256 * 64) + k * 64 + (n & 63)];
  unsigned short hi = f2bf(v);
  Bh[i] = hi;
  Bl[i] = f2bf(v - bf2f(hi));
}

// ---- pack Wf [256][40] -> [64][256] bf16 hi/lo, zero rows 40..63
__global__ void pack_wf_bf(const float* __restrict__ Wf,
                           unsigned short* __restrict__ Bh,
                           unsigned short* __restrict__ Bl) {
  int i = blockIdx.x * 256 + threadIdx.x;   // i = n*256 + k, n<64
  if (i >= 64 * 256) return;
  int n = i >> 8, k = i & 255;
  float v = (n < NCLS) ? Wf[k * NCLS + n] : 0.f;
  unsigned short hi = f2bf(v);
  Bh[i] = hi;
  Bl[i] = f2bf(v - bf2f(hi));
}

// ---- split fp32 [*][256] -> bf16 hi/lo (for GEMM A operand)
__global__ void split_bf(const float* __restrict__ A,
                         unsigned short* __restrict__ Ah,
                         unsigned short* __restrict__ Al, int n4) {
  int i = blockIdx.x * 256 + threadIdx.x;
  if (i >= n4) return;
  float4 v = ((const float4*)A)[i];
  ushort4 h, l;
  h.x = f2bf(v.x); l.x = f2bf(v.x - bf2f(h.x));
  h.y = f2bf(v.y); l.y = f2bf(v.y - bf2f(h.y));
  h.z = f2bf(v.z); l.z = f2bf(v.z - bf2f(h.z));
  h.w = f2bf(v.w); l.w = f2bf(v.w - bf2f(h.w));
  ((ushort4*)Ah)[i] = h;
  ((ushort4*)Al)[i] = l;
}

// ---- fp32 -> bf16 (rounded) for gather ft
__global__ void tobf16(const float* __restrict__ A,
                       unsigned short* __restrict__ B, int n4) {
  int i = blockIdx.x * 256 + threadIdx.x;
  if (i >= n4) return;
  float4 v = ((const float4*)A)[i];
  ushort4 h;
  h.x = f2bf(v.x); h.y = f2bf(v.y); h.z = f2bf(v.z); h.w = f2bf(v.w);
  ((ushort4*)B)[i] = h;
}

// ---- bf16x3 MFMA GEMM: C[M x Nc] = A[M x 256] @ Bt^T + bias
// A pre-split into Ah/Al bf16 [M][256]; Bt stored [Npad][256] bf16 (hi,lo).
template <int BN>
__global__ __launch_bounds__(256) void gemm_bf16x3(
    const unsigned short* __restrict__ Ah, const unsigned short* __restrict__ Al,
    const unsigned short* __restrict__ Bth, const unsigned short* __restrict__ Btl,
    const float* __restrict__ bias, float* __restrict__ C,
    int M, int Nc) {
  constexpr int K = 256;
  constexpr int RS = 40;                 // LDS row stride (ushorts): 80B -> 2-way max
  constexpr int WM = (BN == 128) ? 2 : 4;   // waves along M
  constexpr int WN = 4 / WM;                // waves along N
  constexpr int MI = (128 / WM) / 16;       // 4 or 2
  constexpr int NI = (BN / WN) / 16;        // 4

  __shared__ unsigned short sAh[128 * RS];
  __shared__ unsigned short sAl[128 * RS];
  __shared__ unsigned short sBh[BN * RS];
  __shared__ unsigned short sBl[BN * RS];

  const int tid = threadIdx.x;
  const int lane = tid & 63;
  const int w = tid >> 6;
  const int wr = w / WN, wc = w % WN;
  const int rowbase = wr * (128 / WM);
  const int colbase = wc * (BN / WN);
  const int row0 = blockIdx.x * 128;
  const int col0 = blockIdx.y * BN;
  const int lm = lane & 15;
  const int lk8 = (lane >> 4) * 8;

  f4v acc[MI][NI];
#pragma unroll
  for (int i = 0; i < MI; i++)
#pragma unroll
    for (int j = 0; j < NI; j++) acc[i][j] = (f4v)(0.f);

  for (int k0 = 0; k0 < K; k0 += 32) {
    __syncthreads();
    // stage A 128x32 bf16 hi/lo (pre-split)
#pragma unroll
    for (int i = 0; i < 2; ++i) {
      int idx = tid + i * 256;            // 0..511
      int r = idx >> 2, seg = idx & 3;
      int grow = row0 + r;
      s8v hv = (s8v)(short)0, lv = (s8v)(short)0;
      if (grow < M) {
        size_t g = (size_t)grow * K + k0 + seg * 8;
        hv = *(const s8v*)(Ah + g);
        lv = *(const s8v*)(Al + g);
      }
      *(s8v*)&sAh[r * RS + seg * 8] = hv;
      *(s8v*)&sAl[r * RS + seg * 8] = lv;
    }
    // stage B BNx32 bf16 hi/lo (pre-transposed [n][k])
#pragma unroll
    for (int i = 0; i < BN / 64; ++i) {
      int idx = tid + i * 256;            // < BN*4
      int n = idx >> 2, seg = idx & 3;
      size_t g = (size_t)(col0 + n) * K + k0 + seg * 8;
      *(s8v*)&sBh[n * RS + seg * 8] = *(const s8v*)(Bth + g);
      *(s8v*)&sBl[n * RS + seg * 8] = *(const s8v*)(Btl + g);
    }
    __syncthreads();

    s8v ah[MI], al_[MI], bh[NI], bl_[NI];
#pragma unroll
    for (int mi = 0; mi < MI; ++mi) {
      int base = (rowbase + mi * 16 + lm) * RS + lk8;
      ah[mi] = *(const s8v*)&sAh[base];
      al_[mi] = *(const s8v*)&sAl[base];
    }
#pragma unroll
    for (int ni = 0; ni < NI; ++ni) {
      int base = (colbase + ni * 16 + lm) * RS + lk8;
      bh[ni] = *(const s8v*)&sBh[base];
      bl_[ni] = *(const s8v*)&sBl[base];
    }
    // pass 1: hi*hi
#pragma unroll
    for (int mi = 0; mi < MI; ++mi)
#pragma unroll
      for (int ni = 0; ni < NI; ++ni)
        acc[mi][ni] = __builtin_amdgcn_mfma_f32_16x16x32_bf16(ah[mi], bh[ni], acc[mi][ni], 0, 0, 0);
    // pass 2: hi*lo
#pragma unroll
    for (int mi = 0; mi < MI; ++mi)
#pragma unroll
      for (int ni = 0; ni < NI; ++ni)
        acc[mi][ni] = __builtin_amdgcn_mfma_f32_16x16x32_bf16(ah[mi], bl_[ni], acc[mi][ni], 0, 0, 0);
    // pass 3: lo*hi
#pragma unroll
    for (int mi = 0; mi < MI; ++mi)
#pragma unroll
      for (int ni = 0; ni < NI; ++ni)
        acc[mi][ni] = __builtin_amdgcn_mfma_f32_16x16x32_bf16(al_[mi], bh[ni], acc[mi][ni], 0, 0, 0);
  }

  // epilogue: C = acc + bias  (D map: col=lane&15, row=(lane>>4)*4+r)
#pragma unroll
  for (int ni = 0; ni < NI; ++ni) {
    int col = col0 + colbase + ni * 16 + lm;
    if (col >= Nc) continue;
    float bv = bias[col];
#pragma unroll
    for (int mi = 0; mi < MI; ++mi) {
      int rbase = row0 + rowbase + mi * 16 + (lane >> 4) * 4;
#pragma unroll
      for (int r = 0; r < 4; ++r) {
        int row = rbase + r;
        if (row < M) C[(size_t)row * Nc + col] = acc[mi][ni][r] + bv;
      }
    }
  }
}

// ---- per-node attention scores, 4 heads over 256 dims (one wave per node)
__global__ void attn_scores4(const float* __restrict__ ft,
                             const float* __restrict__ al, const float* __restrict__ alb,
                             const float* __restrict__ ar, const float* __restrict__ arb,
                             float* __restrict__ a1, float* __restrict__ a2, int n_nodes) {
  int n = blockIdx.x * 4 + (threadIdx.x >> 6);
  if (n >= n_nodes) return;
  int lane = threadIdx.x & 63;
  float4 f = *(const float4*)(ft + (size_t)n * 256 + lane * 4);
  float4 l4 = *(const float4*)(al + lane * 4);
  float4 r4 = *(const float4*)(ar + lane * 4);
  float p1 = f.x * l4.x + f.y * l4.y + f.z * l4.z + f.w * l4.w;
  float p2 = f.x * r4.x + f.y * r4.y + f.z * r4.z + f.w * r4.w;
#pragma unroll
  for (int m = 1; m < 16; m <<= 1) {
    p1 += __shfl_xor(p1, m);
    p2 += __shfl_xor(p2, m);
  }
  if ((lane & 15) == 0) {
    int h = lane >> 4;
    a1[n * 4 + h] = p1 + alb[h];
    a2[n * 4 + h] = p2 + arb[h];
  }
}

// ---- final-layer attention scores (1 head over 40 dims)
__global__ void attn_scores1(const float* __restrict__ ftf,
                             const float* __restrict__ alf, const float* __restrict__ alfb,
                             const float* __restrict__ arf, const float* __restrict__ arfb,
                             float* __restrict__ a1, float* __restrict__ a2, int n_nodes) {
  int n = blockIdx.x * 4 + (threadIdx.x >> 6);
  if (n >= n_nodes) return;
  int lane = threadIdx.x & 63;
  float v = (lane < NCLS) ? ftf[(size_t)n * NCLS + lane] : 0.f;
  float p1 = (lane < NCLS) ? v * alf[lane] : 0.f;
  float p2 = (lane < NCLS) ? v * arf[lane] : 0.f;
#pragma unroll
  for (int m = 1; m < 64; m <<= 1) {
    p1 += __shfl_xor(p1, m);
    p2 += __shfl_xor(p2, m);
  }
  if (lane == 0) {
    a1[n] = p1 + alfb[0];
    a2[n] = p2 + arfb[0];
  }
}

// ---- CSR build
__global__ void count_deg(const int* __restrict__ dst, int* __restrict__ deg) {
  int e = blockIdx.x * blockDim.x + threadIdx.x;
  if (e < NE) atomicAdd(&deg[dst[e]], 1);
}

__global__ void scan_deg(const int* __restrict__ deg, int* __restrict__ row_ptr, int n) {
  __shared__ int partials[1024];
  int t = threadIdx.x;
  int chunk = (n + 1023) >> 10;
  int base = t * chunk;
  int lim = min(base + chunk, n);
  int sum = 0;
  for (int i = base; i < lim; ++i) sum += deg[i];
  partials[t] = sum;
  __syncthreads();
  for (int off = 1; off < 1024; off <<= 1) {
    int v = (t >= off) ? partials[t - off] : 0;
    __syncthreads();
    partials[t] += v;
    __syncthreads();
  }
  int run = (t == 0) ? 0 : partials[t - 1];
  if (t == 0) row_ptr[0] = 0;
  for (int i = base; i < lim; ++i) {
    run += deg[i];
    row_ptr[i + 1] = run;
  }
}

__global__ void copy_int(const int* __restrict__ a, int* __restrict__ b, int n) {
  int i = blockIdx.x * blockDim.x + threadIdx.x;
  if (i < n) b[i] = a[i];
}

__global__ void scatter_e(const int* __restrict__ dst, int* __restrict__ cursor,
                          int* __restrict__ eidx) {
  int e = blockIdx.x * blockDim.x + threadIdx.x;
  if (e >= NE) return;
  int d = dst[e];
  int pos = atomicAdd(&cursor[d], 1);
  eidx[pos] = e;
}

// ---- wave-per-node fused gather (4 heads, D=256), bf16 ft, register staging.
// out[n] = elu(res[n] + (sum_e ft[src_e]*w_e) / (sum_e w_e))  per head
__global__ __launch_bounds__(256) void gather_wave4(
    const unsigned short* __restrict__ ftb, const float* __restrict__ a1,
    const float* __restrict__ a2, const float* __restrict__ res,
    const int* __restrict__ row_ptr, const int* __restrict__ eidx,
    const int* __restrict__ src, float* __restrict__ out) {
  const int n = blockIdx.x * 4 + (threadIdx.x >> 6);
  if (n >= NN) return;
  const int lane = threadIdx.x & 63;
  const int c = lane >> 4;            // head for my 4 columns
  const int b = row_ptr[n], en = row_ptr[n + 1];
  const int deg = en - b;
  const float4 a1v = *(const float4*)(a1 + (size_t)n * 4);
  float4 accv = make_float4(0.f, 0.f, 0.f, 0.f);
  float den = 0.f;

  for (int cb = 0; cb < deg; cb += 64) {
    int cnt = min(64, deg - cb);
    int s = 0;
    float4 wv = make_float4(0.f, 0.f, 0.f, 0.f);
    if (lane < cnt) {
      s = src[eidx[b + cb + lane]];
      float4 as_ = *(const float4*)(a2 + (size_t)s * 4);
      wv.x = lrelu_exp(as_.x + a1v.x);
      wv.y = lrelu_exp(as_.y + a1v.y);
      wv.z = lrelu_exp(as_.z + a1v.z);
      wv.w = lrelu_exp(as_.w + a1v.w);
    }
    for (int i = 0; i < cnt; ++i) {
      int si = __builtin_amdgcn_readlane(s, i);
      float fx = rdlanef(wv.x, i);
      float fy = rdlanef(wv.y, i);
      float fz = rdlanef(wv.z, i);
      float fw = rdlanef(wv.w, i);
      float wc = (c == 0) ? fx : (c == 1) ? fy : (c == 2) ? fz : fw;
      ushort4 fv = *(const ushort4*)(ftb + (size_t)si * DD + lane * 4);
      accv.x = fmaf(bf2f(fv.x), wc, accv.x);
      accv.y = fmaf(bf2f(fv.y), wc, accv.y);
      accv.z = fmaf(bf2f(fv.z), wc, accv.z);
      accv.w = fmaf(bf2f(fv.w), wc, accv.w);
      den += wc;
    }
  }
  float invden = (deg > 0) ? 1.f / den : 0.f;
  float4 r = (res != nullptr) ? *(const float4*)(res + (size_t)n * DD + lane * 4)
                              : make_float4(0.f, 0.f, 0.f, 0.f);
  float4 o;
  o.x = elu_f(r.x + accv.x * invden);
  o.y = elu_f(r.y + accv.y * invden);
  o.z = elu_f(r.z + accv.z * invden);
  o.w = elu_f(r.w + accv.w * invden);
  *(float4*)(out + (size_t)n * DD + lane * 4) = o;
}

// ---- fused gather (1 head, D=NCLS=40), fp32 ft
__global__ __launch_bounds__(64) void gather_fused1(
    const float* __restrict__ ft, const float* __restrict__ a1,
    const float* __restrict__ a2, const float* __restrict__ res,
    const int* __restrict__ row_ptr, const int* __restrict__ eidx,
    const int* __restrict__ src, float* __restrict__ out) {
  const int n = blockIdx.x;
  const int d = threadIdx.x;
  const int b = row_ptr[n], en = row_ptr[n + 1];
  const int deg = en - b;
  const float a1n = a1[n];
  float acc = 0.f;
  float den = 0.f;

  for (int cb = 0; cb < deg; cb += 64) {
    int cnt = min(64, deg - cb);
    int s = 0;
    float wv = 0.f;
    if (d < cnt) {
      s = src[eidx[b + cb + d]];
      wv = lrelu_exp(a2[s] + a1n);
    }
    for (int i = 0; i < cnt; ++i) {
      int si = __builtin_amdgcn_readlane(s, i);
      float wi = rdlanef(wv, i);
      if (d < NCLS) acc = fmaf(ft[(size_t)si * NCLS + d], wi, acc);
      den += wi;
    }
  }
  float invden = (deg > 0) ? 1.f / den : 0.f;
  if (d < NCLS) {
    float r = res[(size_t)n * NCLS + d];
    out[(size_t)n * NCLS + d] = elu_f(r + acc * invden);
  }
}

extern "C" void kernel_launch(void* const* d_in, const int* in_sizes, int n_in,
                              void* d_out, int out_size, void* d_ws, size_t ws_size,
                              hipStream_t stream) {
  const float* features = (const float*)d_in[0];
  const int* src = (const int*)d_in[1];
  const int* dst = (const int*)d_in[2];
  const float* W0 = (const float*)d_in[3];
  const float* b0 = (const float*)d_in[4];
  const float* al0 = (const float*)d_in[5];
  const float* alb0 = (const float*)d_in[6];
  const float* ar0 = (const float*)d_in[7];
  const float* arb0 = (const float*)d_in[8];
  const float* W1 = (const float*)d_in[9];
  const float* b1 = (const float*)d_in[10];
  const float* al1 = (const float*)d_in[11];
  const float* alb1 = (const float*)d_in[12];
  const float* ar1 = (const float*)d_in[13];
  const float* arb1 = (const float*)d_in[14];
  const float* R1 = (const float*)d_in[15];
  const float* Rb1 = (const float*)d_in[16];
  const float* Wf = (const float*)d_in[17];
  const float* bfc = (const float*)d_in[18];
  const float* alf = (const float*)d_in[19];
  const float* alfb = (const float*)d_in[20];
  const float* arf = (const float*)d_in[21];
  const float* arfb = (const float*)d_in[22];
  const float* Rf = (const float*)d_in[23];
  const float* Rbf = (const float*)d_in[24];
  float* out = (float*)d_out;

  float* p = (float*)d_ws;
  float* B1 = p;  p += (size_t)NN * 256;
  float* B2 = p;  p += (size_t)NN * 256;
  float* B3 = p;  p += (size_t)NN * 256;
  float* a1 = p;  p += (size_t)NN * 4;
  float* a2 = p;  p += (size_t)NN * 4;
  unsigned short* us = (unsigned short*)p;
  unsigned short* Wp0h = us; us += 65536;
  unsigned short* Wp0l = us; us += 65536;
  unsigned short* Wp1h = us; us += 65536;
  unsigned short* Wp1l = us; us += 65536;
  unsigned short* Rp1h = us; us += 65536;
  unsigned short* Rp1l = us; us += 65536;
  unsigned short* Wfh = us;  us += 64 * 256;
  unsigned short* Wfl = us;  us += 64 * 256;
  unsigned short* Rfh = us;  us += 64 * 256;
  unsigned short* Rfl = us;  us += 64 * 256;
  unsigned short* Ah = us;   us += (size_t)NN * 256;
  unsigned short* Al = us;   us += (size_t)NN * 256;
  unsigned short* ftb = us;  us += (size_t)NN * 256;
  int* ip = (int*)us;
  int* row_ptr = ip; ip += NN + 1;
  int* cursor = ip;  ip += NN;
  int* deg = ip;     ip += NN;
  int* eidx = ip;    ip += NE;

  const int EB = (NE + 255) / 256;
  const int N4 = NN * 64;            // NN*256/4 float4 elements

  // weight packing + bf16 hi/lo split ([H][K][HID] -> [n][k])
  pack_w_bf<<<256, 256, 0, stream>>>(W0, Wp0h, Wp0l);
  pack_w_bf<<<256, 256, 0, stream>>>(W1, Wp1h, Wp1l);
  pack_w_bf<<<256, 256, 0, stream>>>(R1, Rp1h, Rp1l);
  pack_wf_bf<<<64, 256, 0, stream>>>(Wf, Wfh, Wfl);
  pack_wf_bf<<<64, 256, 0, stream>>>(Rf, Rfh, Rfl);

  // CSR by dst (built once, reused by all 3 layers)
  hipMemsetAsync(deg, 0, NN * sizeof(int), stream);
  count_deg<<<EB, 256, 0, stream>>>(dst, deg);
  scan_deg<<<1, 1024, 0, stream>>>(deg, row_ptr, NN);
  copy_int<<<(NN + 255) / 256, 256, 0, stream>>>(row_ptr, cursor, NN);
  scatter_e<<<EB, 256, 0, stream>>>(dst, cursor, eidx);

  const int MB = (NN + 127) / 128;   // 391
  dim3 gbig(MB, 2);
  dim3 gsm(MB, 1);
  const int GW = (NN + 3) / 4;       // wave-per-node gather grid

  // ---- layer 0
  split_bf<<<(N4 + 255) / 256, 256, 0, stream>>>(features, Ah, Al, N4);
  gemm_bf16x3<128><<<gbig, 256, 0, stream>>>(Ah, Al, Wp0h, Wp0l, b0, B1, NN, 256);
  attn_scores4<<<(NN + 3) / 4, 256, 0, stream>>>(B1, al0, alb0, ar0, arb0, a1, a2, NN);
  tobf16<<<(N4 + 255) / 256, 256, 0, stream>>>(B1, ftb, N4);
  gather_wave4<<<GW, 256, 0, stream>>>(ftb, a1, a2, nullptr, row_ptr, eidx, src, B2);

  // ---- layer 1 (residual)
  split_bf<<<(N4 + 255) / 256, 256, 0, stream>>>(B2, Ah, Al, N4);
  gemm_bf16x3<128><<<gbig, 256, 0, stream>>>(Ah, Al, Wp1h, Wp1l, b1, B1, NN, 256);
  gemm_bf16x3<128><<<gbig, 256, 0, stream>>>(Ah, Al, Rp1h, Rp1l, Rb1, B3, NN, 256);
  attn_scores4<<<(NN + 3) / 4, 256, 0, stream>>>(B1, al1, alb1, ar1, arb1, a1, a2, NN);
  tobf16<<<(N4 + 255) / 256, 256, 0, stream>>>(B1, ftb, N4);
  gather_wave4<<<GW, 256, 0, stream>>>(ftb, a1, a2, B3, row_ptr, eidx, src, B3);

  // ---- final layer (residual, 1 head, 40 classes)
  split_bf<<<(N4 + 255) / 256, 256, 0, stream>>>(B3, Ah, Al, N4);
  gemm_bf16x3<64><<<gsm, 256, 0, stream>>>(Ah, Al, Wfh, Wfl, bfc, B1, NN, NCLS);
  gemm_bf16x3<64><<<gsm, 256, 0, stream>>>(Ah, Al, Rfh, Rfl, Rbf, B2, NN, NCLS);
  attn_scores1<<<(NN + 3) / 4, 256, 0, stream>>>(B1, alf, alfb, arf, arfb, a1, a2, NN);
  gather_fused1<<<NN, 64, 0, stream>>>(B1, a1, a2, B2, row_ptr, eidx, src, out);
}

// Round 5
// 734.533 us; speedup vs baseline: 1.9581x; 1.0987x over previous
//
#include <hip/hip_runtime.h>
#include <hip/hip_bf16.h>
#include <math.h>

#define NN   50000
#define NE   800000
#define NHEAD 4
#define HIDD 64
#define DD   256   // NHEAD*HIDD
#define NCLS 40

typedef __attribute__((ext_vector_type(8))) short s8v;    // 8 x bf16 bits
typedef __attribute__((ext_vector_type(4))) float f4v;

static __device__ __forceinline__ float elu_f(float x) {
  return x > 0.f ? x : expm1f(x);
}
static __device__ __forceinline__ float lrelu_exp(float x) {
  float v = x > 0.f ? x : 0.01f * x;
  return expf(v);
}
static __device__ __forceinline__ unsigned short f2bf(float x) {
  union { float f; unsigned u; } v; v.f = x;
  unsigned r = v.u + 0x7fffu + ((v.u >> 16) & 1u);   // RNE
  return (unsigned short)(r >> 16);
}
static __device__ __forceinline__ float bf2f(unsigned short b) {
  union { unsigned u; float f; } v; v.u = ((unsigned)b) << 16;
  return v.f;
}
static __device__ __forceinline__ float rdlanef(float v, int l) {
  return __uint_as_float(__builtin_amdgcn_readlane(__float_as_uint(v), l));
}

// ---- pack W [H][256][64] -> Bt_hi/lo [n=h*64+c][k] bf16 (row-major n x 256)
__global__ void pack_w_bf(const float* __restrict__ W,
                          unsigned short* __restrict__ Bh,
                          unsigned short* __restrict__ Bl) {
  int i = blockIdx.x * 256 + threadIdx.x;   // i = n*256 + k
  if (i >= 65536) return;
  int n = i >> 8, k = i & 255;
  float v = W[(n >> 6) * (256 * 64) + k * 64 + (n & 63)];
  unsigned short hi = f2bf(v);
  Bh[i] = hi;
  Bl[i] = f2bf(v - bf2f(hi));
}

// ---- pack Wf [256][40] -> [64][256] bf16 hi/lo, zero rows 40..63
__global__ void pack_wf_bf(const float* __restrict__ Wf,
                           unsigned short* __restrict__ Bh,
                           unsigned short* __restrict__ Bl) {
  int i = blockIdx.x * 256 + threadIdx.x;   // i = n*256 + k, n<64
  if (i >= 64 * 256) return;
  int n = i >> 8, k = i & 255;
  float v = (n < NCLS) ? Wf[k * NCLS + n] : 0.f;
  unsigned short hi = f2bf(v);
  Bh[i] = hi;
  Bl[i] = f2bf(v - bf2f(hi));
}

// ---- split fp32 [*][256] -> bf16 hi/lo (features only; layer outputs fuse this)
__global__ void split_bf(const float* __restrict__ A,
                         unsigned short* __restrict__ Ah,
                         unsigned short* __restrict__ Al, int n4) {
  int i = blockIdx.x * 256 + threadIdx.x;
  if (i >= n4) return;
  float4 v = ((const float4*)A)[i];
  ushort4 h, l;
  h.x = f2bf(v.x); l.x = f2bf(v.x - bf2f(h.x));
  h.y = f2bf(v.y); l.y = f2bf(v.y - bf2f(h.y));
  h.z = f2bf(v.z); l.z = f2bf(v.z - bf2f(h.z));
  h.w = f2bf(v.w); l.w = f2bf(v.w - bf2f(h.w));
  ((ushort4*)Ah)[i] = h;
  ((ushort4*)Al)[i] = l;
}

// ---- bf16x3 MFMA GEMM: C[M x Nc] = A[M x 256] @ Bt^T + bias
// A pre-split into Ah/Al bf16 [M][256]; Bt stored [Npad][256] bf16 (hi,lo).
// OBF=1: write bf16 to Cb; OBF=0: write fp32 to C.
template <int BN, int OBF>
__global__ __launch_bounds__(256) void gemm_bf16x3(
    const unsigned short* __restrict__ Ah, const unsigned short* __restrict__ Al,
    const unsigned short* __restrict__ Bth, const unsigned short* __restrict__ Btl,
    const float* __restrict__ bias, float* __restrict__ C,
    unsigned short* __restrict__ Cb,
    int M, int Nc) {
  constexpr int K = 256;
  constexpr int RS = 40;                 // LDS row stride (ushorts): 80B -> 2-way max
  constexpr int WM = (BN == 128) ? 2 : 4;   // waves along M
  constexpr int WN = 4 / WM;                // waves along N
  constexpr int MI = (128 / WM) / 16;       // 4 or 2
  constexpr int NI = (BN / WN) / 16;        // 4

  __shared__ unsigned short sAh[128 * RS];
  __shared__ unsigned short sAl[128 * RS];
  __shared__ unsigned short sBh[BN * RS];
  __shared__ unsigned short sBl[BN * RS];

  const int tid = threadIdx.x;
  const int lane = tid & 63;
  const int w = tid >> 6;
  const int wr = w / WN, wc = w % WN;
  const int rowbase = wr * (128 / WM);
  const int colbase = wc * (BN / WN);
  const int row0 = blockIdx.x * 128;
  const int col0 = blockIdx.y * BN;
  const int lm = lane & 15;
  const int lk8 = (lane >> 4) * 8;

  f4v acc[MI][NI];
#pragma unroll
  for (int i = 0; i < MI; i++)
#pragma unroll
    for (int j = 0; j < NI; j++) acc[i][j] = (f4v)(0.f);

  for (int k0 = 0; k0 < K; k0 += 32) {
    __syncthreads();
    // stage A 128x32 bf16 hi/lo (pre-split)
#pragma unroll
    for (int i = 0; i < 2; ++i) {
      int idx = tid + i * 256;            // 0..511
      int r = idx >> 2, seg = idx & 3;
      int grow = row0 + r;
      s8v hv = (s8v)(short)0, lv = (s8v)(short)0;
      if (grow < M) {
        size_t g = (size_t)grow * K + k0 + seg * 8;
        hv = *(const s8v*)(Ah + g);
        lv = *(const s8v*)(Al + g);
      }
      *(s8v*)&sAh[r * RS + seg * 8] = hv;
      *(s8v*)&sAl[r * RS + seg * 8] = lv;
    }
    // stage B BNx32 bf16 hi/lo (pre-transposed [n][k])
#pragma unroll
    for (int i = 0; i < BN / 64; ++i) {
      int idx = tid + i * 256;            // < BN*4
      int n = idx >> 2, seg = idx & 3;
      size_t g = (size_t)(col0 + n) * K + k0 + seg * 8;
      *(s8v*)&sBh[n * RS + seg * 8] = *(const s8v*)(Bth + g);
      *(s8v*)&sBl[n * RS + seg * 8] = *(const s8v*)(Btl + g);
    }
    __syncthreads();

    s8v ah[MI], al_[MI], bh[NI], bl_[NI];
#pragma unroll
    for (int mi = 0; mi < MI; ++mi) {
      int base = (rowbase + mi * 16 + lm) * RS + lk8;
      ah[mi] = *(const s8v*)&sAh[base];
      al_[mi] = *(const s8v*)&sAl[base];
    }
#pragma unroll
    for (int ni = 0; ni < NI; ++ni) {
      int base = (colbase + ni * 16 + lm) * RS + lk8;
      bh[ni] = *(const s8v*)&sBh[base];
      bl_[ni] = *(const s8v*)&sBl[base];
    }
    // pass 1: hi*hi
#pragma unroll
    for (int mi = 0; mi < MI; ++mi)
#pragma unroll
      for (int ni = 0; ni < NI; ++ni)
        acc[mi][ni] = __builtin_amdgcn_mfma_f32_16x16x32_bf16(ah[mi], bh[ni], acc[mi][ni], 0, 0, 0);
    // pass 2: hi*lo
#pragma unroll
    for (int mi = 0; mi < MI; ++mi)
#pragma unroll
      for (int ni = 0; ni < NI; ++ni)
        acc[mi][ni] = __builtin_amdgcn_mfma_f32_16x16x32_bf16(ah[mi], bl_[ni], acc[mi][ni], 0, 0, 0);
    // pass 3: lo*hi
#pragma unroll
    for (int mi = 0; mi < MI; ++mi)
#pragma unroll
      for (int ni = 0; ni < NI; ++ni)
        acc[mi][ni] = __builtin_amdgcn_mfma_f32_16x16x32_bf16(al_[mi], bh[ni], acc[mi][ni], 0, 0, 0);
  }

  // epilogue: C = acc + bias  (D map: col=lane&15, row=(lane>>4)*4+r)
#pragma unroll
  for (int ni = 0; ni < NI; ++ni) {
    int col = col0 + colbase + ni * 16 + lm;
    if (col >= Nc) continue;
    float bv = bias[col];
#pragma unroll
    for (int mi = 0; mi < MI; ++mi) {
      int rbase = row0 + rowbase + mi * 16 + (lane >> 4) * 4;
#pragma unroll
      for (int r = 0; r < 4; ++r) {
        int row = rbase + r;
        if (row < M) {
          float o = acc[mi][ni][r] + bv;
          if (OBF) Cb[(size_t)row * Nc + col] = f2bf(o);
          else     C[(size_t)row * Nc + col] = o;
        }
      }
    }
  }
}

// ---- per-node attention scores from bf16 ft, 4 heads over 256 dims
__global__ void attn_scores4_bf(const unsigned short* __restrict__ ftb,
                                const float* __restrict__ al, const float* __restrict__ alb,
                                const float* __restrict__ ar, const float* __restrict__ arb,
                                float* __restrict__ a1, float* __restrict__ a2, int n_nodes) {
  int n = blockIdx.x * 4 + (threadIdx.x >> 6);
  if (n >= n_nodes) return;
  int lane = threadIdx.x & 63;
  ushort4 fb = *(const ushort4*)(ftb + (size_t)n * 256 + lane * 4);
  float4 f = make_float4(bf2f(fb.x), bf2f(fb.y), bf2f(fb.z), bf2f(fb.w));
  float4 l4 = *(const float4*)(al + lane * 4);
  float4 r4 = *(const float4*)(ar + lane * 4);
  float p1 = f.x * l4.x + f.y * l4.y + f.z * l4.z + f.w * l4.w;
  float p2 = f.x * r4.x + f.y * r4.y + f.z * r4.z + f.w * r4.w;
#pragma unroll
  for (int m = 1; m < 16; m <<= 1) {
    p1 += __shfl_xor(p1, m);
    p2 += __shfl_xor(p2, m);
  }
  if ((lane & 15) == 0) {
    int h = lane >> 4;
    a1[n * 4 + h] = p1 + alb[h];
    a2[n * 4 + h] = p2 + arb[h];
  }
}

// ---- final-layer attention scores (1 head over 40 dims, fp32 ft)
__global__ void attn_scores1(const float* __restrict__ ftf,
                             const float* __restrict__ alf, const float* __restrict__ alfb,
                             const float* __restrict__ arf, const float* __restrict__ arfb,
                             float* __restrict__ a1, float* __restrict__ a2, int n_nodes) {
  int n = blockIdx.x * 4 + (threadIdx.x >> 6);
  if (n >= n_nodes) return;
  int lane = threadIdx.x & 63;
  float v = (lane < NCLS) ? ftf[(size_t)n * NCLS + lane] : 0.f;
  float p1 = (lane < NCLS) ? v * alf[lane] : 0.f;
  float p2 = (lane < NCLS) ? v * arf[lane] : 0.f;
#pragma unroll
  for (int m = 1; m < 64; m <<= 1) {
    p1 += __shfl_xor(p1, m);
    p2 += __shfl_xor(p2, m);
  }
  if (lane == 0) {
    a1[n] = p1 + alfb[0];
    a2[n] = p2 + arfb[0];
  }
}

// ---- CSR build
__global__ void count_deg(const int* __restrict__ dst, int* __restrict__ deg) {
  int e = blockIdx.x * blockDim.x + threadIdx.x;
  if (e < NE) atomicAdd(&deg[dst[e]], 1);
}

__global__ void scan_deg(const int* __restrict__ deg, int* __restrict__ row_ptr, int n) {
  __shared__ int partials[1024];
  int t = threadIdx.x;
  int chunk = (n + 1023) >> 10;
  int base = t * chunk;
  int lim = min(base + chunk, n);
  int sum = 0;
  for (int i = base; i < lim; ++i) sum += deg[i];
  partials[t] = sum;
  __syncthreads();
  for (int off = 1; off < 1024; off <<= 1) {
    int v = (t >= off) ? partials[t - off] : 0;
    __syncthreads();
    partials[t] += v;
    __syncthreads();
  }
  int run = (t == 0) ? 0 : partials[t - 1];
  if (t == 0) row_ptr[0] = 0;
  for (int i = base; i < lim; ++i) {
    run += deg[i];
    row_ptr[i + 1] = run;
  }
}

__global__ void copy_int(const int* __restrict__ a, int* __restrict__ b, int n) {
  int i = blockIdx.x * blockDim.x + threadIdx.x;
  if (i < n) b[i] = a[i];
}

__global__ void scatter_e(const int* __restrict__ dst, int* __restrict__ cursor,
                          int* __restrict__ eidx) {
  int e = blockIdx.x * blockDim.x + threadIdx.x;
  if (e >= NE) return;
  int d = dst[e];
  int pos = atomicAdd(&cursor[d], 1);
  eidx[pos] = e;
}

// ---- wave-per-node fused gather (4 heads, D=256), bf16 ft, 4x-unrolled
// edge loop for memory-level parallelism. Writes hi/lo bf16 split directly
// (sole consumer is the next layer's GEMM A operand).
__global__ __launch_bounds__(256) void gather_wave4(
    const unsigned short* __restrict__ ftb, const float* __restrict__ a1,
    const float* __restrict__ a2, const float* __restrict__ res,
    const int* __restrict__ row_ptr, const int* __restrict__ eidx,
    const int* __restrict__ src,
    unsigned short* __restrict__ outh, unsigned short* __restrict__ outl) {
  const int n = blockIdx.x * 4 + (threadIdx.x >> 6);
  if (n >= NN) return;
  const int lane = threadIdx.x & 63;
  const int c = lane >> 4;            // head for my 4 columns
  const int b = row_ptr[n], en = row_ptr[n + 1];
  const int deg = en - b;
  const float4 a1v = *(const float4*)(a1 + (size_t)n * 4);
  float4 accv = make_float4(0.f, 0.f, 0.f, 0.f);
  float den = 0.f;

  for (int cb = 0; cb < deg; cb += 64) {
    int cnt = min(64, deg - cb);
    int s = 0;
    float4 wv = make_float4(0.f, 0.f, 0.f, 0.f);
    if (lane < cnt) {
      s = src[eidx[b + cb + lane]];
      float4 as_ = *(const float4*)(a2 + (size_t)s * 4);
      wv.x = lrelu_exp(as_.x + a1v.x);
      wv.y = lrelu_exp(as_.y + a1v.y);
      wv.z = lrelu_exp(as_.z + a1v.z);
      wv.w = lrelu_exp(as_.w + a1v.w);
    }
    int i = 0;
    for (; i + 4 <= cnt; i += 4) {
      int s0 = __builtin_amdgcn_readlane(s, i + 0);
      int s1 = __builtin_amdgcn_readlane(s, i + 1);
      int s2 = __builtin_amdgcn_readlane(s, i + 2);
      int s3 = __builtin_amdgcn_readlane(s, i + 3);
      ushort4 f0 = *(const ushort4*)(ftb + (size_t)s0 * DD + lane * 4);
      ushort4 f1 = *(const ushort4*)(ftb + (size_t)s1 * DD + lane * 4);
      ushort4 f2 = *(const ushort4*)(ftb + (size_t)s2 * DD + lane * 4);
      ushort4 f3 = *(const ushort4*)(ftb + (size_t)s3 * DD + lane * 4);
      float x0 = rdlanef(wv.x, i + 0), y0 = rdlanef(wv.y, i + 0),
            z0 = rdlanef(wv.z, i + 0), u0 = rdlanef(wv.w, i + 0);
      float x1 = rdlanef(wv.x, i + 1), y1 = rdlanef(wv.y, i + 1),
            z1 = rdlanef(wv.z, i + 1), u1 = rdlanef(wv.w, i + 1);
      float x2 = rdlanef(wv.x, i + 2), y2 = rdlanef(wv.y, i + 2),
            z2 = rdlanef(wv.z, i + 2), u2 = rdlanef(wv.w, i + 2);
      float x3 = rdlanef(wv.x, i + 3), y3 = rdlanef(wv.y, i + 3),
            z3 = rdlanef(wv.z, i + 3), u3 = rdlanef(wv.w, i + 3);
      float w0 = (c == 0) ? x0 : (c == 1) ? y0 : (c == 2) ? z0 : u0;
      float w1 = (c == 0) ? x1 : (c == 1) ? y1 : (c == 2) ? z1 : u1;
      float w2 = (c == 0) ? x2 : (c == 1) ? y2 : (c == 2) ? z2 : u2;
      float w3 = (c == 0) ? x3 : (c == 1) ? y3 : (c == 2) ? z3 : u3;
      accv.x = fmaf(bf2f(f0.x), w0, accv.x);
      accv.y = fmaf(bf2f(f0.y), w0, accv.y);
      accv.z = fmaf(bf2f(f0.z), w0, accv.z);
      accv.w = fmaf(bf2f(f0.w), w0, accv.w);
      accv.x = fmaf(bf2f(f1.x), w1, accv.x);
      accv.y = fmaf(bf2f(f1.y), w1, accv.y);
      accv.z = fmaf(bf2f(f1.z), w1, accv.z);
      accv.w = fmaf(bf2f(f1.w), w1, accv.w);
      accv.x = fmaf(bf2f(f2.x), w2, accv.x);
      accv.y = fmaf(bf2f(f2.y), w2, accv.y);
      accv.z = fmaf(bf2f(f2.z), w2, accv.z);
      accv.w = fmaf(bf2f(f2.w), w2, accv.w);
      accv.x = fmaf(bf2f(f3.x), w3, accv.x);
      accv.y = fmaf(bf2f(f3.y), w3, accv.y);
      accv.z = fmaf(bf2f(f3.z), w3, accv.z);
      accv.w = fmaf(bf2f(f3.w), w3, accv.w);
      den += (w0 + w1) + (w2 + w3);
    }
    for (; i < cnt; ++i) {
      int si = __builtin_amdgcn_readlane(s, i);
      float fx = rdlanef(wv.x, i), fy = rdlanef(wv.y, i),
            fz = rdlanef(wv.z, i), fw = rdlanef(wv.w, i);
      float wc = (c == 0) ? fx : (c == 1) ? fy : (c == 2) ? fz : fw;
      ushort4 fv = *(const ushort4*)(ftb + (size_t)si * DD + lane * 4);
      accv.x = fmaf(bf2f(fv.x), wc, accv.x);
      accv.y = fmaf(bf2f(fv.y), wc, accv.y);
      accv.z = fmaf(bf2f(fv.z), wc, accv.z);
      accv.w = fmaf(bf2f(fv.w), wc, accv.w);
      den += wc;
    }
  }
  float invden = (deg > 0) ? 1.f / den : 0.f;
  float4 r = (res != nullptr) ? *(const float4*)(res + (size_t)n * DD + lane * 4)
                              : make_float4(0.f, 0.f, 0.f, 0.f);
  float4 o;
  o.x = elu_f(r.x + accv.x * invden);
  o.y = elu_f(r.y + accv.y * invden);
  o.z = elu_f(r.z + accv.z * invden);
  o.w = elu_f(r.w + accv.w * invden);
  ushort4 h, l;
  h.x = f2bf(o.x); l.x = f2bf(o.x - bf2f(h.x));
  h.y = f2bf(o.y); l.y = f2bf(o.y - bf2f(h.y));
  h.z = f2bf(o.z); l.z = f2bf(o.z - bf2f(h.z));
  h.w = f2bf(o.w); l.w = f2bf(o.w - bf2f(h.w));
  *(ushort4*)(outh + (size_t)n * DD + lane * 4) = h;
  *(ushort4*)(outl + (size_t)n * DD + lane * 4) = l;
}

// ---- fused gather (1 head, D=NCLS=40), fp32 ft, 4x-unrolled
__global__ __launch_bounds__(64) void gather_fused1(
    const float* __restrict__ ft, const float* __restrict__ a1,
    const float* __restrict__ a2, const float* __restrict__ res,
    const int* __restrict__ row_ptr, const int* __restrict__ eidx,
    const int* __restrict__ src, float* __restrict__ out) {
  const int n = blockIdx.x;
  const int d = threadIdx.x;
  const int b = row_ptr[n], en = row_ptr[n + 1];
  const int deg = en - b;
  const float a1n = a1[n];
  float acc = 0.f;
  float den = 0.f;

  for (int cb = 0; cb < deg; cb += 64) {
    int cnt = min(64, deg - cb);
    int s = 0;
    float wv = 0.f;
    if (d < cnt) {
      s = src[eidx[b + cb + d]];
      wv = lrelu_exp(a2[s] + a1n);
    }
    int i = 0;
    for (; i + 4 <= cnt; i += 4) {
      int s0 = __builtin_amdgcn_readlane(s, i + 0);
      int s1 = __builtin_amdgcn_readlane(s, i + 1);
      int s2 = __builtin_amdgcn_readlane(s, i + 2);
      int s3 = __builtin_amdgcn_readlane(s, i + 3);
      float w0 = rdlanef(wv, i + 0), w1 = rdlanef(wv, i + 1);
      float w2 = rdlanef(wv, i + 2), w3 = rdlanef(wv, i + 3);
      if (d < NCLS) {
        float v0 = ft[(size_t)s0 * NCLS + d];
        float v1 = ft[(size_t)s1 * NCLS + d];
        float v2 = ft[(size_t)s2 * NCLS + d];
        float v3 = ft[(size_t)s3 * NCLS + d];
        acc = fmaf(v0, w0, acc);
        acc = fmaf(v1, w1, acc);
        acc = fmaf(v2, w2, acc);
        acc = fmaf(v3, w3, acc);
      }
      den += (w0 + w1) + (w2 + w3);
    }
    for (; i < cnt; ++i) {
      int si = __builtin_amdgcn_readlane(s, i);
      float wi = rdlanef(wv, i);
      if (d < NCLS) acc = fmaf(ft[(size_t)si * NCLS + d], wi, acc);
      den += wi;
    }
  }
  float invden = (deg > 0) ? 1.f / den : 0.f;
  if (d < NCLS) {
    float r = res[(size_t)n * NCLS + d];
    out[(size_t)n * NCLS + d] = elu_f(r + acc * invden);
  }
}

extern "C" void kernel_launch(void* const* d_in, const int* in_sizes, int n_in,
                              void* d_out, int out_size, void* d_ws, size_t ws_size,
                              hipStream_t stream) {
  const float* features = (const float*)d_in[0];
  const int* src = (const int*)d_in[1];
  const int* dst = (const int*)d_in[2];
  const float* W0 = (const float*)d_in[3];
  const float* b0 = (const float*)d_in[4];
  const float* al0 = (const float*)d_in[5];
  const float* alb0 = (const float*)d_in[6];
  const float* ar0 = (const float*)d_in[7];
  const float* arb0 = (const float*)d_in[8];
  const float* W1 = (const float*)d_in[9];
  const float* b1 = (const float*)d_in[10];
  const float* al1 = (const float*)d_in[11];
  const float* alb1 = (const float*)d_in[12];
  const float* ar1 = (const float*)d_in[13];
  const float* arb1 = (const float*)d_in[14];
  const float* R1 = (const float*)d_in[15];
  const float* Rb1 = (const float*)d_in[16];
  const float* Wf = (const float*)d_in[17];
  const float* bfc = (const float*)d_in[18];
  const float* alf = (const float*)d_in[19];
  const float* alfb = (const float*)d_in[20];
  const float* arf = (const float*)d_in[21];
  const float* arfb = (const float*)d_in[22];
  const float* Rf = (const float*)d_in[23];
  const float* Rbf = (const float*)d_in[24];
  float* out = (float*)d_out;

  float* p = (float*)d_ws;
  float* B1 = p;  p += (size_t)NN * 256;   // final ft (fp32, 40 cols used)
  float* B2 = p;  p += (size_t)NN * 256;   // final res (fp32, 40 cols used)
  float* B3 = p;  p += (size_t)NN * 256;   // layer-1 residual (fp32)
  float* a1 = p;  p += (size_t)NN * 4;
  float* a2 = p;  p += (size_t)NN * 4;
  unsigned short* us = (unsigned short*)p;
  unsigned short* Wp0h = us; us += 65536;
  unsigned short* Wp0l = us; us += 65536;
  unsigned short* Wp1h = us; us += 65536;
  unsigned short* Wp1l = us; us += 65536;
  unsigned short* Rp1h = us; us += 65536;
  unsigned short* Rp1l = us; us += 65536;
  unsigned short* Wfh = us;  us += 64 * 256;
  unsigned short* Wfl = us;  us += 64 * 256;
  unsigned short* Rfh = us;  us += 64 * 256;
  unsigned short* Rfl = us;  us += 64 * 256;
  unsigned short* Ah = us;   us += (size_t)NN * 256;
  unsigned short* Al = us;   us += (size_t)NN * 256;
  unsigned short* ftb = us;  us += (size_t)NN * 256;
  int* ip = (int*)us;
  int* row_ptr = ip; ip += NN + 1;
  int* cursor = ip;  ip += NN;
  int* deg = ip;     ip += NN;
  int* eidx = ip;    ip += NE;

  const int EB = (NE + 255) / 256;
  const int N4 = NN * 64;            // NN*256/4 float4 elements

  // weight packing + bf16 hi/lo split ([H][K][HID] -> [n][k])
  pack_w_bf<<<256, 256, 0, stream>>>(W0, Wp0h, Wp0l);
  pack_w_bf<<<256, 256, 0, stream>>>(W1, Wp1h, Wp1l);
  pack_w_bf<<<256, 256, 0, stream>>>(R1, Rp1h, Rp1l);
  pack_wf_bf<<<64, 256, 0, stream>>>(Wf, Wfh, Wfl);
  pack_wf_bf<<<64, 256, 0, stream>>>(Rf, Rfh, Rfl);

  // CSR by dst (built once, reused by all 3 layers)
  hipMemsetAsync(deg, 0, NN * sizeof(int), stream);
  count_deg<<<EB, 256, 0, stream>>>(dst, deg);
  scan_deg<<<1, 1024, 0, stream>>>(deg, row_ptr, NN);
  copy_int<<<(NN + 255) / 256, 256, 0, stream>>>(row_ptr, cursor, NN);
  scatter_e<<<EB, 256, 0, stream>>>(dst, cursor, eidx);

  const int MB = (NN + 127) / 128;   // 391
  dim3 gbig(MB, 2);
  dim3 gsm(MB, 1);
  const int GW = (NN + 3) / 4;       // wave-per-node gather grid

  // ---- layer 0
  split_bf<<<(N4 + 255) / 256, 256, 0, stream>>>(features, Ah, Al, N4);
  gemm_bf16x3<128, 1><<<gbig, 256, 0, stream>>>(Ah, Al, Wp0h, Wp0l, b0, nullptr, ftb, NN, 256);
  attn_scores4_bf<<<(NN + 3) / 4, 256, 0, stream>>>(ftb, al0, alb0, ar0, arb0, a1, a2, NN);
  gather_wave4<<<GW, 256, 0, stream>>>(ftb, a1, a2, nullptr, row_ptr, eidx, src, Ah, Al);

  // ---- layer 1 (residual): gathers write Ah/Al for the next GEMMs
  gemm_bf16x3<128, 1><<<gbig, 256, 0, stream>>>(Ah, Al, Wp1h, Wp1l, b1, nullptr, ftb, NN, 256);
  gemm_bf16x3<128, 0><<<gbig, 256, 0, stream>>>(Ah, Al, Rp1h, Rp1l, Rb1, B3, nullptr, NN, 256);
  attn_scores4_bf<<<(NN + 3) / 4, 256, 0, stream>>>(ftb, al1, alb1, ar1, arb1, a1, a2, NN);
  gather_wave4<<<GW, 256, 0, stream>>>(ftb, a1, a2, B3, row_ptr, eidx, src, Ah, Al);

  // ---- final layer (residual, 1 head, 40 classes)
  gemm_bf16x3<64, 0><<<gsm, 256, 0, stream>>>(Ah, Al, Wfh, Wfl, bfc, B1, nullptr, NN, NCLS);
  gemm_bf16x3<64, 0><<<gsm, 256, 0, stream>>>(Ah, Al, Rfh, Rfl, Rbf, B2, nullptr, NN, NCLS);
  attn_scores1<<<(NN + 3) / 4, 256, 0, stream>>>(B1, alf, alfb, arf, arfb, a1, a2, NN);
  gather_fused1<<<NN, 64, 0, stream>>>(B1, a1, a2, B2, row_ptr, eidx, src, out);
}